// Round 10
// baseline (5229.745 us; speedup 1.0000x reference)
//
#include <hip/hip_runtime.h>
#include <hip/hip_fp16.h>
#include <math.h>

namespace {

constexpr int kB = 256;
constexpr int kT = 128;
constexpr int kFC = 128;
constexpr int kNACT = 82;
constexpr int kWDIM = 300;
constexpr int kPOS = 50;

typedef _Float16 v4h __attribute__((ext_vector_type(4)));
typedef float f32x4 __attribute__((ext_vector_type(4)));

__device__ __forceinline__ float sigf(float x) { return 1.0f / (1.0f + expf(-x)); }

// Coherent (LLC) 8B load, issue-only: result NOT ready until s_waitcnt vmcnt.
__device__ __forceinline__ void ld_llc_v4h(const _Float16* p, v4h& dst) {
  asm volatile("global_load_dwordx2 %0, %1, off sc0 sc1"
               : "=v"(dst)
               : "v"(p));
}
// Coherent (LLC) 8B store (write-through; bypasses stale per-XCD L2).
__device__ __forceinline__ void st_llc_v4h(_Float16* p, v4h v) {
  asm volatile("global_store_dwordx2 %0, %1, off sc0 sc1"
               :: "v"(p), "v"(v) : "memory");
}

// Team barrier: per-block arrival flags. Explicit vmcnt(0) drains this wave's
// exchange stores; __syncthreads joins all waves; thread 0 publishes; all
// waves poll the 16-flag line coalesced and exit independently.
__device__ __forceinline__ void team_arrive_wait(int* flags, int g, int target) {
  asm volatile("s_waitcnt vmcnt(0)" ::: "memory");
  __syncthreads();
  if (threadIdx.x == 0)
    __hip_atomic_store(flags + g, target, __ATOMIC_RELAXED, __HIP_MEMORY_SCOPE_AGENT);
  const int lane = threadIdx.x & 63;
  for (;;) {
    int f = __hip_atomic_load(flags + (lane & 15), __ATOMIC_RELAXED, __HIP_MEMORY_SCOPE_AGENT);
    if (__all(f >= target)) break;
    __builtin_amdgcn_s_sleep(1);
  }
}

// 4x4 transpose across lane quads: 4 regs x (rows) -> 4 regs x (gates).
__device__ __forceinline__ void quadT(int lane, float& a0, float& a1, float& a2, float& a3) {
  {
    bool odd = lane & 1;
    float s0 = odd ? a0 : a1;
    float s1 = odd ? a2 : a3;
    float r0 = __shfl_xor(s0, 1);
    float r1 = __shfl_xor(s1, 1);
    if (odd) { a0 = r0; a2 = r1; } else { a1 = r0; a3 = r1; }
  }
  {
    bool hi = lane & 2;
    float s0 = hi ? a0 : a2;
    float s1 = hi ? a1 : a3;
    float r0 = __shfl_xor(s0, 2);
    float r1 = __shfl_xor(s1, 2);
    if (hi) { a0 = r0; a1 = r1; } else { a2 = r0; a3 = r1; }
  }
}

// 4 ntiles (full 64 gate cols of this block) x 1 kt: 4 B-frag reads + 4 MFMAs.
__device__ __forceinline__ void mfma4(const _Float16* wt, int arow, int kg, v4h a,
                                      f32x4* acc) {
  const _Float16* wp = wt + kg * 256 + arow * 4;
#pragma unroll
  for (int nt = 0; nt < 4; ++nt) {
    v4h b = *(const v4h*)(wp + nt * 64);
    acc[nt] = __builtin_amdgcn_mfma_f32_16x16x16f16(a, b, acc[nt], 0, 0, 0);
  }
}

// ---------------------------------------------------------------------------
// Reorder W (K,1024) fp32 -> fp16 team layout:
// Wr[g][kt][kg][cs][ki] with col' = g*64+cs = 4u+gate, k = kt*16+kg*4+ki.
// ---------------------------------------------------------------------------
__global__ void reorder_team_kernel(const float* __restrict__ W, _Float16* __restrict__ Wr,
                                    int Ktiles, int D, int Dpad, int gstride, int total) {
  int idx = blockIdx.x * 256 + threadIdx.x;
  if (idx >= total) return;
  int per = Ktiles << 10;
  int g = idx / per;
  int rem = idx - g * per;
  int kt = rem >> 10;
  int r2 = rem & 1023;
  int kg = r2 >> 8, cs = (r2 >> 2) & 63, ki = r2 & 3;
  int k = kt * 16 + kg * 4 + ki;
  int src = (k < Dpad) ? ((k < D) ? k : -1) : (D + (k - Dpad));
  int colp = g * 64 + cs;
  int u = colp >> 2, gate = colp & 3;
  _Float16 v = (_Float16)0.f;
  if (src >= 0) v = (_Float16)W[(size_t)src * 1024 + gate * 256 + u];
  Wr[(size_t)g * gstride + rem] = v;
}

// ---------------------------------------------------------------------------
// Embeddings: relu(concat(W_word[wid], W_pos[pid]) @ emb_W + emb_b)
// ---------------------------------------------------------------------------
__global__ __launch_bounds__(128) void emb_kernel(
    const int* __restrict__ twid, const int* __restrict__ tpid,
    const int* __restrict__ bwid, const int* __restrict__ bpid,
    const float* __restrict__ W_word, const float* __restrict__ W_pos,
    const float* __restrict__ emb_W, const float* __restrict__ emb_b,
    float* __restrict__ tree_emb, _Float16* __restrict__ buff16) {
  __shared__ float xs[8][352];
  const int tid = threadIdx.x;
  const int pair0 = blockIdx.x * 8;
  const int NTREE = kB * kT;

  for (int p = 0; p < 8; ++p) {
    int P = pair0 + p;
    bool isTree = P < NTREE;
    int idx = isTree ? P : P - NTREE;
    int wid = isTree ? twid[idx] : bwid[idx];
    int pid = isTree ? tpid[idx] : bpid[idx];
    const float* wrow = W_word + (size_t)wid * kWDIM;
    for (int k = tid; k < kWDIM; k += 128) xs[p][k] = wrow[k];
    if (tid < kPOS) xs[p][kWDIM + tid] = W_pos[pid * kPOS + tid];
  }
  __syncthreads();

  float acc[8];
  const float bj = emb_b[tid];
#pragma unroll
  for (int p = 0; p < 8; ++p) acc[p] = bj;

#pragma unroll 10
  for (int k = 0; k < kWDIM + kPOS; ++k) {
    float w = emb_W[k * kFC + tid];
#pragma unroll
    for (int p = 0; p < 8; ++p) acc[p] = fmaf(xs[p][k], w, acc[p]);
  }

  for (int p = 0; p < 8; ++p) {
    int P = pair0 + p;
    bool isTree = P < NTREE;
    int idx = isTree ? P : P - NTREE;
    float v = fmaxf(acc[p], 0.0f);
    if (isTree) tree_emb[(size_t)idx * kFC + tid] = v;
    else buff16[(size_t)idx * kFC + tid] = (_Float16)v;
  }
}

// ---------------------------------------------------------------------------
// Tree composition scan: one block per batch row, res[128][128] in LDS, fp16 out.
// ---------------------------------------------------------------------------
__global__ __launch_bounds__(128) void tree_scan_kernel(
    const float* __restrict__ tree_emb,
    const int* __restrict__ head_ord, const int* __restrict__ dep_ord,
    const int* __restrict__ rel_id, const int* __restrict__ is_leaf,
    const float* __restrict__ W_rel,
    const float* __restrict__ rec_W, const float* __restrict__ rec_b,
    _Float16* __restrict__ res16) {
  __shared__ float res[kT][kFC];
  const int b = blockIdx.x;
  const int j = threadIdx.x;

  res[0][j] = tree_emb[((size_t)b * kT) * kFC + j];
  const float rb = rec_b[j];
  __syncthreads();

  for (int i = 1; i < kT; ++i) {
    const int base = b * kT + i;
    const int leaf = is_leaf[base];
    if (leaf > 0) {
      res[i][j] = tree_emb[(size_t)base * kFC + j];
    } else {
      const int hi = head_ord[base];
      const int di = dep_ord[base];
      const int rid = rel_id[base];
      float acc = rb;
#pragma unroll 8
      for (int k = 0; k < 128; ++k)
        acc = fmaf(res[hi][k], rec_W[k * kFC + j], acc);
#pragma unroll 5
      for (int k = 0; k < 50; ++k)
        acc = fmaf(W_rel[rid * 50 + k], rec_W[(128 + k) * kFC + j], acc);
#pragma unroll 8
      for (int k = 0; k < 128; ++k)
        acc = fmaf(res[di][k], rec_W[(178 + k) * kFC + j], acc);
      res[i][j] = tanhf(acc);
    }
    __syncthreads();
  }

  for (int idx = j; idx < kT * kFC; idx += 128) {
    int t = idx >> 7;
    int jj = idx & 127;
    res16[((size_t)b * kT + t) * kFC + jj] = (_Float16)res[t][jj];
  }
}

// ---------------------------------------------------------------------------
// Persistent-weight team LSTM, k-parity wave split (ks = wave&1):
// each wave computes ALL 4 column-ntiles for every other kt -> per-wave
// exchange loads halve (24 vs 48) and no wave-pair duplication remains.
// Cross-ks partial sums are reduced through a conflict-free LDS buffer.
// Exchange tiles keep the fragment-coalesced layout ex[mt][kt][kg][arow][ki].
// ---------------------------------------------------------------------------
template <int MODE, int Dt, int K1t, int STEPS>
__device__ void team_lstm(
    int g, int row0, const _Float16* wlds, _Float16* stage, float* red,
    const void* xsrc, const int* __restrict__ order,
    const int* __restrict__ lengths,
    const float* __restrict__ b1, const float* __restrict__ b2,
    _Float16* exch, int* flags, float* __restrict__ hcat, int hoff) {
  static_assert(K1t - Dt == 16, "h1 tile must be 16 k-tiles");
  const int tid = threadIdx.x, lane = tid & 63;
  const int wave = tid >> 6, mt = wave >> 1, ks = wave & 1;
  const int arow = lane & 15, kg = lane >> 4;
  const int prow = kg * 4 + (lane & 3);
  const int ul = arow >> 2;

  _Float16* nh1b[2] = {exch, exch + 16384};
  _Float16* h1b[2] = {exch + 32768, exch + 49152};
  _Float16* h2b[2] = {exch + 65536, exch + 81920};

  const int growA = row0 + mt * 16 + arow;
  const int growP = row0 + mt * 16 + prow;
  const int lenP = lengths[growP];

  // consumer base into fragment-coalesced tile: 8*lane bytes within a kt slab
  const int cbase = mt * 4096 + kg * 64 + arow * 4;

  float bi1[2][4], bi2[2][4];
#pragma unroll
  for (int n = 0; n < 2; ++n) {
    int ug = g * 16 + (2 * ks + n) * 4 + ul;
#pragma unroll
    for (int q = 0; q < 4; ++q) {
      bi1[n][q] = b1[q * 256 + ug];
      bi2[n][q] = b2[q * 256 + ug];
    }
  }
  float c1[2] = {0.f, 0.f}, h1st[2] = {0.f, 0.f};
  float c2[2] = {0.f, 0.f}, h2st[2] = {0.f, 0.f};
  const _Float16* w2 = wlds + K1t * 1024;

  for (int p = 0; p <= STEPS; ++p) {
    const int rd = (p + 1) & 1, wr = p & 1;
    const _Float16* h1rd = h1b[rd];
    const _Float16* nh1rd = nh1b[rd];
    const _Float16* h2rd = h2b[rd];
    f32x4 acc1[4], acc2[4];
#pragma unroll
    for (int n = 0; n < 4; ++n) { acc1[n] = 0.f; acc2[n] = 0.f; }

    // ---- issue this wave's half of the exchange loads (coalesced) ----
    v4h ar1[8], ar2[16];
    if (p < STEPS) {
#pragma unroll
      for (int i = 0; i < 8; ++i)
        ld_llc_v4h(h1rd + cbase + (2 * i + ks) * 256, ar1[i]);
    }
    if (p > 0) {
#pragma unroll
      for (int i = 0; i < 8; ++i)
        ld_llc_v4h(nh1rd + cbase + (2 * i + ks) * 256, ar2[i]);
#pragma unroll
      for (int i = 0; i < 8; ++i)
        ld_llc_v4h(h2rd + cbase + (2 * i + ks) * 256, ar2[8 + i]);
    }

    // ---- layer 1 x-part (this wave's kt parity; overlaps load latency) ----
    if (p < STEPS) {
      if constexpr (MODE == 2) {
        int aid = order[growA * 256 + p];
        const float* xp = (const float*)xsrc + (size_t)aid * 50;
#pragma unroll
        for (int kt = ks; kt < Dt; kt += 2) {
          v4h a;
#pragma unroll
          for (int i = 0; i < 4; ++i) {
            int kk = kt * 16 + kg * 4 + i;
            a[i] = (kk < 50) ? (_Float16)xp[kk] : (_Float16)0.f;
          }
          mfma4(wlds + kt * 1024, arow, kg, a, acc1);
        }
      } else {
        const _Float16* x16 = (const _Float16*)xsrc;
        const _Float16* xp;
        if constexpr (MODE == 0) {
          int so = order[growA * 128 + p];
          xp = x16 + ((size_t)growA * 128 + so) * 128;
        } else {
          xp = x16 + ((size_t)growA * 128 + p) * 128;
        }
#pragma unroll
        for (int kt = ks; kt < Dt; kt += 2) {
          v4h a = *(const v4h*)(xp + kt * 16 + kg * 4);
          mfma4(wlds + kt * 1024, arow, kg, a, acc1);
        }
      }
    }

    // ---- single drain for the exchange batch; fence MFMA hoisting ----
    asm volatile("s_waitcnt vmcnt(0)" ::: "memory");
    __builtin_amdgcn_sched_barrier(0);

    // ---- layer 1 h-part + layer 2, from registers (this wave's kts) ----
    if (p < STEPS) {
#pragma unroll
      for (int i = 0; i < 8; ++i)
        mfma4(wlds + (Dt + 2 * i + ks) * 1024, arow, kg, ar1[i], acc1);
    }
    if (p > 0) {
#pragma unroll
      for (int i = 0; i < 8; ++i)
        mfma4(w2 + (2 * i + ks) * 1024, arow, kg, ar2[i], acc2);
#pragma unroll
      for (int i = 0; i < 8; ++i)
        mfma4(w2 + (16 + 2 * i + ks) * 1024, arow, kg, ar2[8 + i], acc2);
    }

    // ---- cross-ks reduction via LDS (conflict-free b32 planes) ----
    // red[wave][slot(4)][comp(4)][lane(64)] f32; slots 0,1 = acc1 partner
    // ntiles, 2,3 = acc2 partner ntiles. Partner wave = wave^1.
    {
      int pnt0 = 2 * (ks ^ 1);
#pragma unroll
      for (int j = 0; j < 2; ++j) {
#pragma unroll
        for (int c = 0; c < 4; ++c) {
          red[((wave * 4 + j) * 4 + c) * 64 + lane] = acc1[pnt0 + j][c];
          red[((wave * 4 + 2 + j) * 4 + c) * 64 + lane] = acc2[pnt0 + j][c];
        }
      }
    }
    __syncthreads();
    {
      int pw = wave ^ 1;
#pragma unroll
      for (int j = 0; j < 2; ++j) {
        int mynt = 2 * ks + j;
#pragma unroll
        for (int c = 0; c < 4; ++c) {
          acc1[mynt][c] += red[((pw * 4 + j) * 4 + c) * 64 + lane];
          acc2[mynt][c] += red[((pw * 4 + 2 + j) * 4 + c) * 64 + lane];
        }
      }
    }

    // ---- pointwise layer 1 -> LDS stage ----
    if (p < STEPS) {
#pragma unroll
      for (int n = 0; n < 2; ++n) {
        int nt = 2 * ks + n;
        float g0 = acc1[nt][0], g1 = acc1[nt][1], g2 = acc1[nt][2], g3 = acc1[nt][3];
        quadT(lane, g0, g1, g2, g3);
        float nc = sigf(g2 + bi1[n][2] + 1.f) * c1[n] + sigf(g0 + bi1[n][0]) * tanhf(g1 + bi1[n][1]);
        float nh = sigf(g3 + bi1[n][3]) * tanhf(nc);
        int cl = ks * 8 + n * 4 + ul;
        stage[(mt * 16 + prow) * 16 + cl] = (_Float16)nh;           // UNMASKED
        if (p < lenP) { c1[n] = nc; h1st[n] = nh; }
        stage[1024 + (mt * 16 + prow) * 16 + cl] = (_Float16)h1st[n];
      }
    }
    // ---- pointwise layer 2 (t = p-1) -> LDS stage ----
    if (p > 0) {
#pragma unroll
      for (int n = 0; n < 2; ++n) {
        int nt = 2 * ks + n;
        float g0 = acc2[nt][0], g1 = acc2[nt][1], g2 = acc2[nt][2], g3 = acc2[nt][3];
        quadT(lane, g0, g1, g2, g3);
        float nc = sigf(g2 + bi2[n][2] + 1.f) * c2[n] + sigf(g0 + bi2[n][0]) * tanhf(g1 + bi2[n][1]);
        float nh = sigf(g3 + bi2[n][3]) * tanhf(nc);
        int cl = ks * 8 + n * 4 + ul;
        if (p - 1 < lenP) { c2[n] = nc; h2st[n] = nh; }
        stage[2048 + (mt * 16 + prow) * 16 + cl] = (_Float16)h2st[n];
      }
    }
    __syncthreads();  // stage tiles complete

    // ---- cooperative coalesced store into fragment layout ----
    for (int i = tid; i < 768; i += 512) {
      int tile = i >> 8;        // 0=nh1, 1=h1, 2=h2
      int rem = i & 255;
      int mtd = rem >> 6, kgd = (rem >> 4) & 3, ard = rem & 15;
      bool go = (tile == 2) ? (p > 0) : (p < STEPS);
      if (go) {
        v4h v = *(const v4h*)(stage + tile * 1024 + (mtd * 16 + ard) * 16 + kgd * 4);
        _Float16* dst = (tile == 0) ? nh1b[wr] : (tile == 1) ? h1b[wr] : h2b[wr];
        st_llc_v4h(dst + mtd * 4096 + g * 256 + kgd * 64 + ard * 4, v);
      }
    }

    if (p < STEPS) team_arrive_wait(flags, g, p + 1);
  }

#pragma unroll
  for (int n = 0; n < 2; ++n) {
    int ug = g * 16 + (2 * ks + n) * 4 + ul;
    hcat[(size_t)growP * 768 + hoff + ug] = h2st[n];
  }
}

// 12 teams x 16 blocks = 192 blocks. Team->XCD packing (perf heuristic only;
// correctness is placement-independent via LLC-coherent exchange).
__global__ __launch_bounds__(512, 2) void lstm_team_kernel(
    const _Float16* res16, const _Float16* buff16, const float* W_act,
    const int* sord, const int* haid,
    const int* slen, const int* blen, const int* alen,
    const _Float16* sWr, const _Float16* bWr, const _Float16* aWr,
    const float* sb1, const float* sb2, const float* bb1, const float* bb2,
    const float* ab1, const float* ab2,
    _Float16* exch, int* ctrs, float* hcat) {
  __shared__ __align__(16) _Float16 wlds[57344];  // 112 KB weight slice
  __shared__ __align__(16) _Float16 stage[3072];  // 6 KB pointwise staging
  __shared__ __align__(16) float red[8 * 4 * 4 * 64];  // 32 KB ks-reduction

  const int bid = blockIdx.x;
  const int xcd = bid & 7, slot = bid >> 3;
  int tau, g;
  if (slot < 16) { tau = xcd; g = slot; }
  else { tau = 8 + (xcd >> 1); g = (slot - 16) + ((xcd & 1) ? 8 : 0); }

  const _Float16* wsrc;
  int wn;
  if (tau < 4) { wsrc = sWr + (size_t)g * 57344; wn = 57344; }
  else if (tau < 8) { wsrc = bWr + (size_t)g * 57344; wn = 57344; }
  else { wsrc = aWr + (size_t)g * 53248; wn = 53248; }
  for (int i = threadIdx.x * 8; i < wn; i += 512 * 8)
    *(float4*)&wlds[i] = *(const float4*)&wsrc[i];
  __syncthreads();

  _Float16* ex = exch + (size_t)tau * 98304;
  int* flags = ctrs + tau * 32;

  if (tau < 4) {
    team_lstm<0, 8, 24, 128>(g, tau * 64, wlds, stage, red, res16, sord, slen, sb1, sb2, ex, flags, hcat, 0);
  } else if (tau < 8) {
    team_lstm<1, 8, 24, 128>(g, (tau - 4) * 64, wlds, stage, red, buff16, nullptr, blen, bb1, bb2, ex, flags, hcat, 256);
  } else {
    team_lstm<2, 4, 20, 256>(g, (tau - 8) * 64, wlds, stage, red, W_act, haid, alen, ab1, ab2, ex, flags, hcat, 512);
  }
}

// ---------------------------------------------------------------------------
// Final projection: out[b] = hcat[b] @ fW + fb   (256 x 768) @ (768 x 82)
// ---------------------------------------------------------------------------
__global__ __launch_bounds__(128) void final_kernel(
    const float* __restrict__ hcat, const float* __restrict__ fW,
    const float* __restrict__ fb, float* __restrict__ out) {
  __shared__ float hrow[768];
  const int b = blockIdx.x;
  const int tid = threadIdx.x;
  for (int k = tid; k < 768; k += 128) hrow[k] = hcat[(size_t)b * 768 + k];
  __syncthreads();
  if (tid < kNACT) {
    float acc = fb[tid];
#pragma unroll 8
    for (int k = 0; k < 768; ++k) acc = fmaf(hrow[k], fW[k * kNACT + tid], acc);
    out[(size_t)b * kNACT + tid] = acc;
  }
}

}  // namespace

extern "C" void kernel_launch(void* const* d_in, const int* in_sizes, int n_in,
                              void* d_out, int out_size, void* d_ws, size_t ws_size,
                              hipStream_t stream) {
  const int* twid = (const int*)d_in[0];
  const int* tpid = (const int*)d_in[1];
  const int* bwid = (const int*)d_in[2];
  const int* bpid = (const int*)d_in[3];
  const int* relid = (const int*)d_in[4];
  const int* haid = (const int*)d_in[5];
  const int* head = (const int*)d_in[6];
  const int* depo = (const int*)d_in[7];
  const int* leaf = (const int*)d_in[8];
  const int* sord = (const int*)d_in[9];
  const int* slen = (const int*)d_in[10];
  const int* blen = (const int*)d_in[11];
  const int* alen = (const int*)d_in[12];
  const float* W_word = (const float*)d_in[13];
  const float* W_pos = (const float*)d_in[14];
  const float* W_rel = (const float*)d_in[15];
  const float* W_act = (const float*)d_in[16];
  const float* emb_W = (const float*)d_in[17];
  const float* emb_b = (const float*)d_in[18];
  const float* rec_W = (const float*)d_in[19];
  const float* rec_b = (const float*)d_in[20];
  const float* sW1 = (const float*)d_in[21];
  const float* sb1 = (const float*)d_in[22];
  const float* sW2 = (const float*)d_in[23];
  const float* sb2 = (const float*)d_in[24];
  const float* bW1 = (const float*)d_in[25];
  const float* bb1 = (const float*)d_in[26];
  const float* bW2 = (const float*)d_in[27];
  const float* bb2 = (const float*)d_in[28];
  const float* aW1 = (const float*)d_in[29];
  const float* ab1 = (const float*)d_in[30];
  const float* aW2 = (const float*)d_in[31];
  const float* ab2 = (const float*)d_in[32];
  const float* fW = (const float*)d_in[33];
  const float* fb = (const float*)d_in[34];

  // ---- workspace carve-up ----
  char* w = (char*)d_ws;
  float* tree_emb = (float*)w;            w += (size_t)kB * kT * kFC * 4;
  _Float16* buff16 = (_Float16*)w;        w += (size_t)kB * kT * kFC * 2;
  _Float16* res16 = (_Float16*)w;         w += (size_t)kB * kT * kFC * 2;
  float* hcat = (float*)w;                w += (size_t)kB * 768 * 4;
  _Float16* sWr = (_Float16*)w;           w += (size_t)57344 * 16 * 2;
  _Float16* bWr = (_Float16*)w;           w += (size_t)57344 * 16 * 2;
  _Float16* aWr = (_Float16*)w;           w += (size_t)53248 * 16 * 2;
  _Float16* exch = (_Float16*)w;          w += (size_t)12 * 98304 * 2;
  int* ctrs = (int*)w;                    w += (size_t)12 * 32 * 4;
  size_t needed = (size_t)(w - (char*)d_ws);
  if (ws_size < needed) return;

  // 0) zero exchange buffers + barrier flags (every launch; deterministic)
  (void)hipMemsetAsync(exch, 0, (size_t)12 * 98304 * 2 + (size_t)12 * 32 * 4, stream);

  // 1) team-layout fp16 weight reorder
  auto reorder = [&](const float* W, _Float16* Wr, int Kt, int D, int Dpad, int gstride) {
    int total = 16 * Kt * 1024;
    reorder_team_kernel<<<(total + 255) / 256, 256, 0, stream>>>(W, Wr, Kt, D, Dpad, gstride, total);
  };
  reorder(sW1, sWr, 24, 128, 128, 57344);
  reorder(sW2, sWr + 24 * 1024, 32, 512, 512, 57344);
  reorder(bW1, bWr, 24, 128, 128, 57344);
  reorder(bW2, bWr + 24 * 1024, 32, 512, 512, 57344);
  reorder(aW1, aWr, 20, 50, 64, 53248);
  reorder(aW2, aWr + 20 * 1024, 32, 512, 512, 53248);

  // 2) embeddings (tree f32, buff fp16)
  emb_kernel<<<(2 * kB * kT) / 8, 128, 0, stream>>>(
      twid, tpid, bwid, bpid, W_word, W_pos, emb_W, emb_b, tree_emb, buff16);

  // 3) tree composition scan -> fp16
  tree_scan_kernel<<<kB, 128, 0, stream>>>(
      tree_emb, head, depo, relid, leaf, W_rel, rec_W, rec_b, res16);

  // 4) persistent-weight team LSTMs (cooperative: residency guarantee)
  {
    const _Float16* a0 = res16; const _Float16* a1 = buff16; const float* a2 = W_act;
    const int* a3 = sord; const int* a4 = haid;
    const int* a5 = slen; const int* a6 = blen; const int* a7 = alen;
    const _Float16* a8 = sWr; const _Float16* a9 = bWr; const _Float16* a10 = aWr;
    const float* a11 = sb1; const float* a12 = sb2; const float* a13 = bb1; const float* a14 = bb2;
    const float* a15 = ab1; const float* a16 = ab2;
    _Float16* a17 = exch; int* a18 = ctrs; float* a19 = hcat;
    void* kargs[] = {&a0, &a1, &a2, &a3, &a4, &a5, &a6, &a7, &a8, &a9, &a10,
                     &a11, &a12, &a13, &a14, &a15, &a16, &a17, &a18, &a19};
    (void)hipLaunchCooperativeKernel((const void*)lstm_team_kernel, dim3(192), dim3(512),
                                     kargs, 0, stream);
  }

  // 5) output projection
  final_kernel<<<kB, 128, 0, stream>>>(hcat, fW, fb, (float*)d_out);
}

// Round 12
// 4281.505 us; speedup vs baseline: 1.2215x; 1.2215x over previous
//
#include <hip/hip_runtime.h>
#include <hip/hip_fp16.h>
#include <math.h>

namespace {

constexpr int kB = 256;
constexpr int kT = 128;
constexpr int kFC = 128;
constexpr int kNACT = 82;
constexpr int kWDIM = 300;
constexpr int kPOS = 50;

typedef _Float16 v4h __attribute__((ext_vector_type(4)));
typedef float f32x4 __attribute__((ext_vector_type(4)));

__device__ __forceinline__ float sigf(float x) { return 1.0f / (1.0f + expf(-x)); }

// Coherent (LLC) 8B load, issue-only: result NOT ready until s_waitcnt vmcnt.
// sc0 sc1 = LLC-coherent, placement-independent (R9-proven).
__device__ __forceinline__ void ld_llc_v4h(const _Float16* p, v4h& dst) {
  asm volatile("global_load_dwordx2 %0, %1, off sc0 sc1"
               : "=v"(dst)
               : "v"(p));
}
// Coherent (LLC) 8B store (write-through; bypasses stale per-XCD L2).
__device__ __forceinline__ void st_llc_v4h(_Float16* p, v4h v) {
  asm volatile("global_store_dwordx2 %0, %1, off sc0 sc1"
               :: "v"(p), "v"(v) : "memory");
}

// Team barrier: per-block arrival flags (agent atomics — proven R9 path).
// vmcnt(0) drains this wave's exchange stores; __syncthreads joins waves;
// thread 0 publishes; all waves poll the 16-flag line coalesced.
__device__ __forceinline__ void team_arrive_wait(int* flags, int g, int target) {
  asm volatile("s_waitcnt vmcnt(0)" ::: "memory");
  __syncthreads();
  if (threadIdx.x == 0)
    __hip_atomic_store(flags + g, target, __ATOMIC_RELAXED, __HIP_MEMORY_SCOPE_AGENT);
  const int lane = threadIdx.x & 63;
  for (;;) {
    int f = __hip_atomic_load(flags + (lane & 15), __ATOMIC_RELAXED, __HIP_MEMORY_SCOPE_AGENT);
    if (__all(f >= target)) break;
    __builtin_amdgcn_s_sleep(1);
  }
}

// 4x4 transpose across lane quads: 4 regs x (rows) -> 4 regs x (gates).
__device__ __forceinline__ void quadT(int lane, float& a0, float& a1, float& a2, float& a3) {
  {
    bool odd = lane & 1;
    float s0 = odd ? a0 : a1;
    float s1 = odd ? a2 : a3;
    float r0 = __shfl_xor(s0, 1);
    float r1 = __shfl_xor(s1, 1);
    if (odd) { a0 = r0; a2 = r1; } else { a1 = r0; a3 = r1; }
  }
  {
    bool hi = lane & 2;
    float s0 = hi ? a0 : a2;
    float s1 = hi ? a1 : a3;
    float r0 = __shfl_xor(s0, 2);
    float r1 = __shfl_xor(s1, 2);
    if (hi) { a0 = r0; a1 = r1; } else { a2 = r0; a3 = r1; }
  }
}

// All 4 ntiles (this block's 64 gate cols) x 1 kt: 4 B-frag reads + 4 MFMAs.
__device__ __forceinline__ void mfma4(const _Float16* wt, int arow, int kg, v4h a,
                                      f32x4* acc) {
  const _Float16* wp = wt + kg * 256 + arow * 4;
#pragma unroll
  for (int n = 0; n < 4; ++n) {
    v4h b = *(const v4h*)(wp + n * 64);
    acc[n] = __builtin_amdgcn_mfma_f32_16x16x16f16(a, b, acc[n], 0, 0, 0);
  }
}

// ---------------------------------------------------------------------------
// Reorder W (K,1024) fp32 -> fp16 team layout:
// Wr[g][kt][kg][cs][ki] with col' = g*64+cs = 4u+gate, k = kt*16+kg*4+ki.
// ---------------------------------------------------------------------------
__global__ void reorder_team_kernel(const float* __restrict__ W, _Float16* __restrict__ Wr,
                                    int Ktiles, int D, int Dpad, int gstride, int total) {
  int idx = blockIdx.x * 256 + threadIdx.x;
  if (idx >= total) return;
  int per = Ktiles << 10;
  int g = idx / per;
  int rem = idx - g * per;
  int kt = rem >> 10;
  int r2 = rem & 1023;
  int kg = r2 >> 8, cs = (r2 >> 2) & 63, ki = r2 & 3;
  int k = kt * 16 + kg * 4 + ki;
  int src = (k < Dpad) ? ((k < D) ? k : -1) : (D + (k - Dpad));
  int colp = g * 64 + cs;
  int u = colp >> 2, gate = colp & 3;
  _Float16 v = (_Float16)0.f;
  if (src >= 0) v = (_Float16)W[(size_t)src * 1024 + gate * 256 + u];
  Wr[(size_t)g * gstride + rem] = v;
}

// ---------------------------------------------------------------------------
// Embeddings: relu(concat(W_word[wid], W_pos[pid]) @ emb_W + emb_b)
// ---------------------------------------------------------------------------
__global__ __launch_bounds__(128) void emb_kernel(
    const int* __restrict__ twid, const int* __restrict__ tpid,
    const int* __restrict__ bwid, const int* __restrict__ bpid,
    const float* __restrict__ W_word, const float* __restrict__ W_pos,
    const float* __restrict__ emb_W, const float* __restrict__ emb_b,
    float* __restrict__ tree_emb, _Float16* __restrict__ buff16) {
  __shared__ float xs[8][352];
  const int tid = threadIdx.x;
  const int pair0 = blockIdx.x * 8;
  const int NTREE = kB * kT;

  for (int p = 0; p < 8; ++p) {
    int P = pair0 + p;
    bool isTree = P < NTREE;
    int idx = isTree ? P : P - NTREE;
    int wid = isTree ? twid[idx] : bwid[idx];
    int pid = isTree ? tpid[idx] : bpid[idx];
    const float* wrow = W_word + (size_t)wid * kWDIM;
    for (int k = tid; k < kWDIM; k += 128) xs[p][k] = wrow[k];
    if (tid < kPOS) xs[p][kWDIM + tid] = W_pos[pid * kPOS + tid];
  }
  __syncthreads();

  float acc[8];
  const float bj = emb_b[tid];
#pragma unroll
  for (int p = 0; p < 8; ++p) acc[p] = bj;

#pragma unroll 10
  for (int k = 0; k < kWDIM + kPOS; ++k) {
    float w = emb_W[k * kFC + tid];
#pragma unroll
    for (int p = 0; p < 8; ++p) acc[p] = fmaf(xs[p][k], w, acc[p]);
  }

  for (int p = 0; p < 8; ++p) {
    int P = pair0 + p;
    bool isTree = P < NTREE;
    int idx = isTree ? P : P - NTREE;
    float v = fmaxf(acc[p], 0.0f);
    if (isTree) tree_emb[(size_t)idx * kFC + tid] = v;
    else buff16[(size_t)idx * kFC + tid] = (_Float16)v;
  }
}

// ---------------------------------------------------------------------------
// Tree composition scan: one block per batch row, res[128][128] f32 in LDS.
// rec_W staged ONCE as fp16 in LDS (78 KB) -> kills the 5.1 GB L2 re-read
// (157 KB x 127 steps x 256 blocks) of the previous version.
// ---------------------------------------------------------------------------
__global__ __launch_bounds__(128) void tree_scan_kernel(
    const float* __restrict__ tree_emb,
    const int* __restrict__ head_ord, const int* __restrict__ dep_ord,
    const int* __restrict__ rel_id, const int* __restrict__ is_leaf,
    const float* __restrict__ W_rel,
    const float* __restrict__ rec_W, const float* __restrict__ rec_b,
    _Float16* __restrict__ res16) {
  __shared__ float res[kT][kFC];          // 64 KB
  __shared__ _Float16 w16[306 * kFC];     // 78336 B
  const int b = blockIdx.x;
  const int j = threadIdx.x;

  for (int idx = j; idx < 306 * kFC; idx += 128)
    w16[idx] = (_Float16)rec_W[idx];

  res[0][j] = tree_emb[((size_t)b * kT) * kFC + j];
  const float rb = rec_b[j];
  __syncthreads();

  const _Float16* wj = w16 + j;
  for (int i = 1; i < kT; ++i) {
    const int base = b * kT + i;
    const int leaf = is_leaf[base];
    if (leaf > 0) {
      res[i][j] = tree_emb[(size_t)base * kFC + j];
    } else {
      const int hi = head_ord[base];
      const int di = dep_ord[base];
      const int rid = rel_id[base];
      float acc = rb;
#pragma unroll 8
      for (int k = 0; k < 128; ++k)
        acc = fmaf(res[hi][k], (float)wj[k * kFC], acc);
#pragma unroll 5
      for (int k = 0; k < 50; ++k)
        acc = fmaf(W_rel[rid * 50 + k], (float)wj[(128 + k) * kFC], acc);
#pragma unroll 8
      for (int k = 0; k < 128; ++k)
        acc = fmaf(res[di][k], (float)wj[(178 + k) * kFC], acc);
      res[i][j] = tanhf(acc);
    }
    __syncthreads();
  }

  for (int idx = j; idx < kT * kFC; idx += 128) {
    int t = idx >> 7;
    int jj = idx & 127;
    res16[((size_t)b * kT + t) * kFC + jj] = (_Float16)res[t][jj];
  }
}

// ---------------------------------------------------------------------------
// Persistent-weight team LSTM, NMT=8: one wave = one 16-row group owning ALL
// 64 gate cols (4 MFMAs/kt). No wave-pair A-fragment duplication -> per-row
// exchange traffic halves vs R9, with NO cross-wave reduction (k not split).
// Teams of 128 rows x 16 blocks. Exchange: fragment-coalesced
// ex[mt][kt][kg][arow][ki], sc0 sc1 LLC ops + agent-atomic flags (R9-proven).
// ---------------------------------------------------------------------------
template <int MODE, int Dt, int K1t, int STEPS>
__device__ void team_lstm(
    int g, int row0, const _Float16* wlds, _Float16* stage,  // stage: [3][128][16]
    const void* xsrc, const int* __restrict__ order,
    const int* __restrict__ lengths,
    const float* __restrict__ b1, const float* __restrict__ b2,
    _Float16* exch, int* flags, float* __restrict__ hcat, int hoff) {
  static_assert(K1t - Dt == 16, "h1 tile must be 16 k-tiles");
  constexpr int TS = 32768;  // halfs per tile-parity: 8 mt * 16 kt * 256
  const int tid = threadIdx.x, lane = tid & 63;
  const int mt = tid >> 6;                 // wave = row-group (0..7)
  const int arow = lane & 15, kg = lane >> 4;
  const int prow = kg * 4 + (lane & 3);
  const int ul = arow >> 2;

  _Float16* nh1b[2] = {exch, exch + TS};
  _Float16* h1b[2] = {exch + 2 * TS, exch + 3 * TS};
  _Float16* h2b[2] = {exch + 4 * TS, exch + 5 * TS};

  const int growA = row0 + mt * 16 + arow;
  const int growP = row0 + mt * 16 + prow;
  const int lenP = lengths[growP];

  // consumer base into fragment-coalesced tile: 8*lane bytes within a kt slab
  const int cbase = mt * 4096 + kg * 64 + arow * 4;

  float bi1[4][4], bi2[4][4];
#pragma unroll
  for (int n = 0; n < 4; ++n) {
    int ug = g * 16 + n * 4 + ul;
#pragma unroll
    for (int q = 0; q < 4; ++q) {
      bi1[n][q] = b1[q * 256 + ug];
      bi2[n][q] = b2[q * 256 + ug];
    }
  }
  float c1[4], h1st[4], c2[4], h2st[4];
#pragma unroll
  for (int n = 0; n < 4; ++n) { c1[n] = h1st[n] = c2[n] = h2st[n] = 0.f; }
  const _Float16* w2 = wlds + K1t * 1024;

  for (int p = 0; p <= STEPS; ++p) {
    const int rd = (p + 1) & 1, wr = p & 1;
    const _Float16* h1rd = h1b[rd];
    const _Float16* nh1rd = nh1b[rd];
    const _Float16* h2rd = h2b[rd];
    f32x4 acc1[4], acc2[4];
#pragma unroll
    for (int n = 0; n < 4; ++n) { acc1[n] = 0.f; acc2[n] = 0.f; }

    // ---- issue ALL exchange loads (coalesced, unique per wave) ----
    v4h ar1[16], ar2[32];
    if (p < STEPS) {
#pragma unroll
      for (int kt = 0; kt < 16; ++kt)
        ld_llc_v4h(h1rd + cbase + kt * 256, ar1[kt]);
    }
    if (p > 0) {
#pragma unroll
      for (int kt = 0; kt < 16; ++kt)
        ld_llc_v4h(nh1rd + cbase + kt * 256, ar2[kt]);
#pragma unroll
      for (int kt = 0; kt < 16; ++kt)
        ld_llc_v4h(h2rd + cbase + kt * 256, ar2[16 + kt]);
    }

    // ---- layer 1 x-part (plain loads; overlaps exchange-load latency) ----
    if (p < STEPS) {
      if constexpr (MODE == 2) {
        int aid = order[growA * 256 + p];
        const float* xp = (const float*)xsrc + (size_t)aid * 50;
#pragma unroll
        for (int kt = 0; kt < Dt; ++kt) {
          v4h a;
#pragma unroll
          for (int i = 0; i < 4; ++i) {
            int kk = kt * 16 + kg * 4 + i;
            a[i] = (kk < 50) ? (_Float16)xp[kk] : (_Float16)0.f;
          }
          mfma4(wlds + kt * 1024, arow, kg, a, acc1);
        }
      } else {
        const _Float16* x16 = (const _Float16*)xsrc;
        const _Float16* xp;
        if constexpr (MODE == 0) {
          int so = order[growA * 128 + p];
          xp = x16 + ((size_t)growA * 128 + so) * 128;
        } else {
          xp = x16 + ((size_t)growA * 128 + p) * 128;
        }
#pragma unroll
        for (int kt = 0; kt < Dt; ++kt) {
          v4h a = *(const v4h*)(xp + kt * 16 + kg * 4);
          mfma4(wlds + kt * 1024, arow, kg, a, acc1);
        }
      }
    }

    // ---- single drain for the exchange batch; fence MFMA hoisting ----
    asm volatile("s_waitcnt vmcnt(0)" ::: "memory");
    __builtin_amdgcn_sched_barrier(0);

    // ---- layer 1 h-part + layer 2, from registers ----
    if (p < STEPS) {
#pragma unroll
      for (int kt = 0; kt < 16; ++kt)
        mfma4(wlds + (Dt + kt) * 1024, arow, kg, ar1[kt], acc1);
    }
    if (p > 0) {
#pragma unroll
      for (int kt = 0; kt < 32; ++kt)
        mfma4(w2 + kt * 1024, arow, kg, ar2[kt], acc2);
    }

    // ---- pointwise layer 1 -> LDS stage ----
    if (p < STEPS) {
#pragma unroll
      for (int n = 0; n < 4; ++n) {
        float g0 = acc1[n][0], g1 = acc1[n][1], g2 = acc1[n][2], g3 = acc1[n][3];
        quadT(lane, g0, g1, g2, g3);
        float nc = sigf(g2 + bi1[n][2] + 1.f) * c1[n] + sigf(g0 + bi1[n][0]) * tanhf(g1 + bi1[n][1]);
        float nh = sigf(g3 + bi1[n][3]) * tanhf(nc);
        int cl = n * 4 + ul;
        stage[(mt * 16 + prow) * 16 + cl] = (_Float16)nh;              // UNMASKED
        if (p < lenP) { c1[n] = nc; h1st[n] = nh; }
        stage[2048 + (mt * 16 + prow) * 16 + cl] = (_Float16)h1st[n];  // masked
      }
    }
    // ---- pointwise layer 2 (t = p-1) -> LDS stage ----
    if (p > 0) {
#pragma unroll
      for (int n = 0; n < 4; ++n) {
        float g0 = acc2[n][0], g1 = acc2[n][1], g2 = acc2[n][2], g3 = acc2[n][3];
        quadT(lane, g0, g1, g2, g3);
        float nc = sigf(g2 + bi2[n][2] + 1.f) * c2[n] + sigf(g0 + bi2[n][0]) * tanhf(g1 + bi2[n][1]);
        float nh = sigf(g3 + bi2[n][3]) * tanhf(nc);
        int cl = n * 4 + ul;
        if (p - 1 < lenP) { c2[n] = nc; h2st[n] = nh; }
        stage[4096 + (mt * 16 + prow) * 16 + cl] = (_Float16)h2st[n];  // masked
      }
    }
    __syncthreads();  // stage tiles complete

    // ---- cooperative coalesced store into fragment layout ----
    // 512 u64 per tile: (mtd 8) x (kgd 4) x (ard 16)
    for (int i = tid; i < 1536; i += 512) {
      int tile = i >> 9;        // 0=nh1, 1=h1, 2=h2
      int rem = i & 511;
      int mtd = rem >> 6, kgd = (rem >> 4) & 3, ard = rem & 15;
      bool go = (tile == 2) ? (p > 0) : (p < STEPS);
      if (go) {
        v4h v = *(const v4h*)(stage + tile * 2048 + (mtd * 16 + ard) * 16 + kgd * 4);
        _Float16* dst = (tile == 0) ? nh1b[wr] : (tile == 1) ? h1b[wr] : h2b[wr];
        st_llc_v4h(dst + mtd * 4096 + g * 256 + kgd * 64 + ard * 4, v);
      }
    }

    if (p < STEPS) team_arrive_wait(flags, g, p + 1);
  }

#pragma unroll
  for (int n = 0; n < 4; ++n) {
    int ug = g * 16 + n * 4 + ul;
    hcat[(size_t)growP * 768 + hoff + ug] = h2st[n];
  }
}

// 6 teams x 16 blocks = 96 blocks, 128 rows per team.
// stack: tau 0-1, buff: tau 2-3, act: tau 4-5 (256 steps).
__global__ __launch_bounds__(512, 2) void lstm_team_kernel(
    const _Float16* res16, const _Float16* buff16, const float* W_act,
    const int* sord, const int* haid,
    const int* slen, const int* blen, const int* alen,
    const _Float16* sWr, const _Float16* bWr, const _Float16* aWr,
    const float* sb1, const float* sb2, const float* bb1, const float* bb2,
    const float* ab1, const float* ab2,
    _Float16* exch, int* ctrs, float* hcat) {
  __shared__ __align__(16) _Float16 wlds[57344];  // 112 KB weight slice
  __shared__ __align__(16) _Float16 stage[6144];  // 12 KB pointwise staging

  const int bid = blockIdx.x;
  const int tau = bid >> 4;
  const int g = bid & 15;

  const _Float16* wsrc;
  int wn;
  if (tau < 4) { wsrc = ((tau < 2) ? sWr : bWr) + (size_t)g * 57344; wn = 57344; }
  else { wsrc = aWr + (size_t)g * 53248; wn = 53248; }
  for (int i = threadIdx.x * 8; i < wn; i += 512 * 8)
    *(float4*)&wlds[i] = *(const float4*)&wsrc[i];
  __syncthreads();

  _Float16* ex = exch + (size_t)tau * 196608;
  int* flags = ctrs + tau * 32;

  if (tau < 2) {
    team_lstm<0, 8, 24, 128>(g, tau * 128, wlds, stage, res16, sord, slen, sb1, sb2, ex, flags, hcat, 0);
  } else if (tau < 4) {
    team_lstm<1, 8, 24, 128>(g, (tau - 2) * 128, wlds, stage, buff16, nullptr, blen, bb1, bb2, ex, flags, hcat, 256);
  } else {
    team_lstm<2, 4, 20, 256>(g, (tau - 4) * 128, wlds, stage, W_act, haid, alen, ab1, ab2, ex, flags, hcat, 512);
  }
}

// ---------------------------------------------------------------------------
// Final projection: out[b] = hcat[b] @ fW + fb   (256 x 768) @ (768 x 82)
// ---------------------------------------------------------------------------
__global__ __launch_bounds__(128) void final_kernel(
    const float* __restrict__ hcat, const float* __restrict__ fW,
    const float* __restrict__ fb, float* __restrict__ out) {
  __shared__ float hrow[768];
  const int b = blockIdx.x;
  const int tid = threadIdx.x;
  for (int k = tid; k < 768; k += 128) hrow[k] = hcat[(size_t)b * 768 + k];
  __syncthreads();
  if (tid < kNACT) {
    float acc = fb[tid];
#pragma unroll 8
    for (int k = 0; k < 768; ++k) acc = fmaf(hrow[k], fW[k * kNACT + tid], acc);
    out[(size_t)b * kNACT + tid] = acc;
  }
}

}  // namespace

extern "C" void kernel_launch(void* const* d_in, const int* in_sizes, int n_in,
                              void* d_out, int out_size, void* d_ws, size_t ws_size,
                              hipStream_t stream) {
  const int* twid = (const int*)d_in[0];
  const int* tpid = (const int*)d_in[1];
  const int* bwid = (const int*)d_in[2];
  const int* bpid = (const int*)d_in[3];
  const int* relid = (const int*)d_in[4];
  const int* haid = (const int*)d_in[5];
  const int* head = (const int*)d_in[6];
  const int* depo = (const int*)d_in[7];
  const int* leaf = (const int*)d_in[8];
  const int* sord = (const int*)d_in[9];
  const int* slen = (const int*)d_in[10];
  const int* blen = (const int*)d_in[11];
  const int* alen = (const int*)d_in[12];
  const float* W_word = (const float*)d_in[13];
  const float* W_pos = (const float*)d_in[14];
  const float* W_rel = (const float*)d_in[15];
  const float* W_act = (const float*)d_in[16];
  const float* emb_W = (const float*)d_in[17];
  const float* emb_b = (const float*)d_in[18];
  const float* rec_W = (const float*)d_in[19];
  const float* rec_b = (const float*)d_in[20];
  const float* sW1 = (const float*)d_in[21];
  const float* sb1 = (const float*)d_in[22];
  const float* sW2 = (const float*)d_in[23];
  const float* sb2 = (const float*)d_in[24];
  const float* bW1 = (const float*)d_in[25];
  const float* bb1 = (const float*)d_in[26];
  const float* bW2 = (const float*)d_in[27];
  const float* bb2 = (const float*)d_in[28];
  const float* aW1 = (const float*)d_in[29];
  const float* ab1 = (const float*)d_in[30];
  const float* aW2 = (const float*)d_in[31];
  const float* ab2 = (const float*)d_in[32];
  const float* fW = (const float*)d_in[33];
  const float* fb = (const float*)d_in[34];

  // ---- workspace carve-up ----
  char* w = (char*)d_ws;
  float* tree_emb = (float*)w;            w += (size_t)kB * kT * kFC * 4;
  _Float16* buff16 = (_Float16*)w;        w += (size_t)kB * kT * kFC * 2;
  _Float16* res16 = (_Float16*)w;         w += (size_t)kB * kT * kFC * 2;
  float* hcat = (float*)w;                w += (size_t)kB * 768 * 4;
  _Float16* sWr = (_Float16*)w;           w += (size_t)57344 * 16 * 2;
  _Float16* bWr = (_Float16*)w;           w += (size_t)57344 * 16 * 2;
  _Float16* aWr = (_Float16*)w;           w += (size_t)53248 * 16 * 2;
  _Float16* exch = (_Float16*)w;          w += (size_t)6 * 196608 * 2;
  int* ctrs = (int*)w;                    w += (size_t)256 * 4;
  size_t needed = (size_t)(w - (char*)d_ws);
  if (ws_size < needed) return;

  // 0) zero exchange buffers + barrier flags (every launch; deterministic)
  (void)hipMemsetAsync(exch, 0, (size_t)6 * 196608 * 2 + (size_t)256 * 4, stream);

  // 1) team-layout fp16 weight reorder
  auto reorder = [&](const float* W, _Float16* Wr, int Kt, int D, int Dpad, int gstride) {
    int total = 16 * Kt * 1024;
    reorder_team_kernel<<<(total + 255) / 256, 256, 0, stream>>>(W, Wr, Kt, D, Dpad, gstride, total);
  };
  reorder(sW1, sWr, 24, 128, 128, 57344);
  reorder(sW2, sWr + 24 * 1024, 32, 512, 512, 57344);
  reorder(bW1, bWr, 24, 128, 128, 57344);
  reorder(bW2, bWr + 24 * 1024, 32, 512, 512, 57344);
  reorder(aW1, aWr, 20, 50, 64, 53248);
  reorder(aW2, aWr + 20 * 1024, 32, 512, 512, 53248);

  // 2) embeddings (tree f32, buff fp16)
  emb_kernel<<<(2 * kB * kT) / 8, 128, 0, stream>>>(
      twid, tpid, bwid, bpid, W_word, W_pos, emb_W, emb_b, tree_emb, buff16);

  // 3) tree composition scan -> fp16 (rec_W staged in LDS)
  tree_scan_kernel<<<kB, 128, 0, stream>>>(
      tree_emb, head, depo, relid, leaf, W_rel, rec_W, rec_b, res16);

  // 4) persistent-weight team LSTMs (cooperative: residency guarantee)
  {
    const _Float16* a0 = res16; const _Float16* a1 = buff16; const float* a2 = W_act;
    const int* a3 = sord; const int* a4 = haid;
    const int* a5 = slen; const int* a6 = blen; const int* a7 = alen;
    const _Float16* a8 = sWr; const _Float16* a9 = bWr; const _Float16* a10 = aWr;
    const float* a11 = sb1; const float* a12 = sb2; const float* a13 = bb1; const float* a14 = bb2;
    const float* a15 = ab1; const float* a16 = ab2;
    _Float16* a17 = exch; int* a18 = ctrs; float* a19 = hcat;
    void* kargs[] = {&a0, &a1, &a2, &a3, &a4, &a5, &a6, &a7, &a8, &a9, &a10,
                     &a11, &a12, &a13, &a14, &a15, &a16, &a17, &a18, &a19};
    (void)hipLaunchCooperativeKernel((const void*)lstm_team_kernel, dim3(96), dim3(512),
                                     kargs, 0, stream);
  }

  // 5) output projection
  final_kernel<<<kB, 128, 0, stream>>>(hcat, fW, fb, (float*)d_out);
}

// Round 13
// 2993.622 us; speedup vs baseline: 1.7470x; 1.4302x over previous
//
#include <hip/hip_runtime.h>
#include <hip/hip_fp16.h>
#include <math.h>

namespace {

constexpr int kB = 256;
constexpr int kT = 128;
constexpr int kFC = 128;
constexpr int kNACT = 82;
constexpr int kWDIM = 300;
constexpr int kPOS = 50;

typedef _Float16 v4h __attribute__((ext_vector_type(4)));
typedef float f32x4 __attribute__((ext_vector_type(4)));

__device__ __forceinline__ float sigf(float x) { return 1.0f / (1.0f + expf(-x)); }

// Coherent (LLC) 8B load, issue-only: result NOT ready until s_waitcnt vmcnt.
__device__ __forceinline__ void ld_llc_v4h(const _Float16* p, v4h& dst) {
  asm volatile("global_load_dwordx2 %0, %1, off sc0 sc1"
               : "=v"(dst)
               : "v"(p));
}
// Coherent (LLC) 8B store (write-through; bypasses stale per-XCD L2).
__device__ __forceinline__ void st_llc_v4h(_Float16* p, v4h v) {
  asm volatile("global_store_dwordx2 %0, %1, off sc0 sc1"
               :: "v"(p), "v"(v) : "memory");
}

// Team barrier: per-block arrival flags (agent atomics — proven path).
// vmcnt(0) drains this wave's exchange stores; __syncthreads joins waves;
// thread 0 publishes; all waves poll the 16-flag line coalesced.
__device__ __forceinline__ void team_arrive_wait(int* flags, int g, int target) {
  asm volatile("s_waitcnt vmcnt(0)" ::: "memory");
  __syncthreads();
  if (threadIdx.x == 0)
    __hip_atomic_store(flags + g, target, __ATOMIC_RELAXED, __HIP_MEMORY_SCOPE_AGENT);
  const int lane = threadIdx.x & 63;
  for (;;) {
    int f = __hip_atomic_load(flags + (lane & 15), __ATOMIC_RELAXED, __HIP_MEMORY_SCOPE_AGENT);
    if (__all(f >= target)) break;
    __builtin_amdgcn_s_sleep(1);
  }
}

// 4x4 transpose across lane quads: 4 regs x (rows) -> 4 regs x (gates).
__device__ __forceinline__ void quadT(int lane, float& a0, float& a1, float& a2, float& a3) {
  {
    bool odd = lane & 1;
    float s0 = odd ? a0 : a1;
    float s1 = odd ? a2 : a3;
    float r0 = __shfl_xor(s0, 1);
    float r1 = __shfl_xor(s1, 1);
    if (odd) { a0 = r0; a2 = r1; } else { a1 = r0; a3 = r1; }
  }
  {
    bool hi = lane & 2;
    float s0 = hi ? a0 : a2;
    float s1 = hi ? a1 : a3;
    float r0 = __shfl_xor(s0, 2);
    float r1 = __shfl_xor(s1, 2);
    if (hi) { a0 = r0; a1 = r1; } else { a2 = r0; a3 = r1; }
  }
}

// B-frag read (bank-conflict-aware) + 2 MFMAs (ntile pair).
__device__ __forceinline__ void mfma_pair(const _Float16* wt, int csA, int kg, v4h a,
                                          f32x4& q0, f32x4& q1) {
  const _Float16* wp = wt + kg * 256 + csA * 4;
  v4h b0 = *(const v4h*)(wp);
  q0 = __builtin_amdgcn_mfma_f32_16x16x16f16(a, b0, q0, 0, 0, 0);
  v4h b1 = *(const v4h*)(wp + 64);
  q1 = __builtin_amdgcn_mfma_f32_16x16x16f16(a, b1, q1, 0, 0, 0);
}

// ---------------------------------------------------------------------------
// Reorder W (K,1024) fp32 -> fp16 team layout:
// Wr[g][kt][kg][cs][ki] with col' = g*64+cs = 4u+gate, k = kt*16+kg*4+ki.
// ---------------------------------------------------------------------------
__global__ void reorder_team_kernel(const float* __restrict__ W, _Float16* __restrict__ Wr,
                                    int Ktiles, int D, int Dpad, int gstride, int total) {
  int idx = blockIdx.x * 256 + threadIdx.x;
  if (idx >= total) return;
  int per = Ktiles << 10;
  int g = idx / per;
  int rem = idx - g * per;
  int kt = rem >> 10;
  int r2 = rem & 1023;
  int kg = r2 >> 8, cs = (r2 >> 2) & 63, ki = r2 & 3;
  int k = kt * 16 + kg * 4 + ki;
  int src = (k < Dpad) ? ((k < D) ? k : -1) : (D + (k - Dpad));
  int colp = g * 64 + cs;
  int u = colp >> 2, gate = colp & 3;
  _Float16 v = (_Float16)0.f;
  if (src >= 0) v = (_Float16)W[(size_t)src * 1024 + gate * 256 + u];
  Wr[(size_t)g * gstride + rem] = v;
}

// ---------------------------------------------------------------------------
// Embeddings: relu(concat(W_word[wid], W_pos[pid]) @ emb_W + emb_b)
// ---------------------------------------------------------------------------
__global__ __launch_bounds__(128) void emb_kernel(
    const int* __restrict__ twid, const int* __restrict__ tpid,
    const int* __restrict__ bwid, const int* __restrict__ bpid,
    const float* __restrict__ W_word, const float* __restrict__ W_pos,
    const float* __restrict__ emb_W, const float* __restrict__ emb_b,
    float* __restrict__ tree_emb, _Float16* __restrict__ buff16) {
  __shared__ float xs[8][352];
  const int tid = threadIdx.x;
  const int pair0 = blockIdx.x * 8;
  const int NTREE = kB * kT;

  for (int p = 0; p < 8; ++p) {
    int P = pair0 + p;
    bool isTree = P < NTREE;
    int idx = isTree ? P : P - NTREE;
    int wid = isTree ? twid[idx] : bwid[idx];
    int pid = isTree ? tpid[idx] : bpid[idx];
    const float* wrow = W_word + (size_t)wid * kWDIM;
    for (int k = tid; k < kWDIM; k += 128) xs[p][k] = wrow[k];
    if (tid < kPOS) xs[p][kWDIM + tid] = W_pos[pid * kPOS + tid];
  }
  __syncthreads();

  float acc[8];
  const float bj = emb_b[tid];
#pragma unroll
  for (int p = 0; p < 8; ++p) acc[p] = bj;

#pragma unroll 10
  for (int k = 0; k < kWDIM + kPOS; ++k) {
    float w = emb_W[k * kFC + tid];
#pragma unroll
    for (int p = 0; p < 8; ++p) acc[p] = fmaf(xs[p][k], w, acc[p]);
  }

  for (int p = 0; p < 8; ++p) {
    int P = pair0 + p;
    bool isTree = P < NTREE;
    int idx = isTree ? P : P - NTREE;
    float v = fmaxf(acc[p], 0.0f);
    if (isTree) tree_emb[(size_t)idx * kFC + tid] = v;
    else buff16[(size_t)idx * kFC + tid] = (_Float16)v;
  }
}

// ---------------------------------------------------------------------------
// Tree composition scan: one block per batch row, res[128][128] f32 in LDS.
// rec_W staged ONCE as fp16 in LDS (78 KB) -> kills the 5.1 GB L2 re-read.
// ---------------------------------------------------------------------------
__global__ __launch_bounds__(128) void tree_scan_kernel(
    const float* __restrict__ tree_emb,
    const int* __restrict__ head_ord, const int* __restrict__ dep_ord,
    const int* __restrict__ rel_id, const int* __restrict__ is_leaf,
    const float* __restrict__ W_rel,
    const float* __restrict__ rec_W, const float* __restrict__ rec_b,
    _Float16* __restrict__ res16) {
  __shared__ float res[kT][kFC];          // 64 KB
  __shared__ _Float16 w16[306 * kFC];     // 78336 B
  const int b = blockIdx.x;
  const int j = threadIdx.x;

  for (int idx = j; idx < 306 * kFC; idx += 128)
    w16[idx] = (_Float16)rec_W[idx];

  res[0][j] = tree_emb[((size_t)b * kT) * kFC + j];
  const float rb = rec_b[j];
  __syncthreads();

  const _Float16* wj = w16 + j;
  for (int i = 1; i < kT; ++i) {
    const int base = b * kT + i;
    const int leaf = is_leaf[base];
    if (leaf > 0) {
      res[i][j] = tree_emb[(size_t)base * kFC + j];
    } else {
      const int hi = head_ord[base];
      const int di = dep_ord[base];
      const int rid = rel_id[base];
      float acc = rb;
#pragma unroll 8
      for (int k = 0; k < 128; ++k)
        acc = fmaf(res[hi][k], (float)wj[k * kFC], acc);
#pragma unroll 5
      for (int k = 0; k < 50; ++k)
        acc = fmaf(W_rel[rid * 50 + k], (float)wj[(128 + k) * kFC], acc);
#pragma unroll 8
      for (int k = 0; k < 128; ++k)
        acc = fmaf(res[di][k], (float)wj[(178 + k) * kFC], acc);
      res[i][j] = tanhf(acc);
    }
    __syncthreads();
  }

  for (int idx = j; idx < kT * kFC; idx += 128) {
    int t = idx >> 7;
    int jj = idx & 127;
    res16[((size_t)b * kT + t) * kFC + jj] = (_Float16)res[t][jj];
  }
}

// ---------------------------------------------------------------------------
// Persistent-weight team LSTM (R9-proven structure, (mt,np) wave split).
// Exchange tiles: fragment-coalesced ex[mt][kt][kg][arow][ki]; sc0 sc1 LLC
// ops + agent-atomic flags. XCD-pure teams make exchange loads local-L2 hits.
// ---------------------------------------------------------------------------
template <int MODE, int Dt, int K1t, int STEPS>
__device__ void team_lstm(
    int g, int row0, const _Float16* wlds, _Float16* stage,  // stage: [3][64][16] LDS
    const void* xsrc, const int* __restrict__ order,
    const int* __restrict__ lengths,
    const float* __restrict__ b1, const float* __restrict__ b2,
    _Float16* exch, int* flags, float* __restrict__ hcat, int hoff) {
  static_assert(K1t - Dt == 16, "h1 tile must be 16 k-tiles");
  const int tid = threadIdx.x, lane = tid & 63;
  const int wave = tid >> 6, mt = wave >> 1, np = wave & 1;
  const int arow = lane & 15, kg = lane >> 4;
  const int prow = kg * 4 + (lane & 3);
  const int ul = arow >> 2;
  const int csA = np * 32 + arow;

  _Float16* nh1b[2] = {exch, exch + 16384};
  _Float16* h1b[2] = {exch + 32768, exch + 49152};
  _Float16* h2b[2] = {exch + 65536, exch + 81920};

  const int growA = row0 + mt * 16 + arow;
  const int growP = row0 + mt * 16 + prow;
  const int lenP = lengths[growP];

  // consumer base into fragment-coalesced tile: 8*lane bytes within a kt slab
  const int cbase = mt * 4096 + kg * 64 + arow * 4;

  float bi1[2][4], bi2[2][4];
#pragma unroll
  for (int n = 0; n < 2; ++n) {
    int ug = g * 16 + (2 * np + n) * 4 + ul;
#pragma unroll
    for (int q = 0; q < 4; ++q) {
      bi1[n][q] = b1[q * 256 + ug];
      bi2[n][q] = b2[q * 256 + ug];
    }
  }
  float c1[2] = {0.f, 0.f}, h1st[2] = {0.f, 0.f};
  float c2[2] = {0.f, 0.f}, h2st[2] = {0.f, 0.f};
  const _Float16* w2 = wlds + K1t * 1024;

  for (int p = 0; p <= STEPS; ++p) {
    const int rd = (p + 1) & 1, wr = p & 1;
    const _Float16* h1rd = h1b[rd];
    const _Float16* nh1rd = nh1b[rd];
    const _Float16* h2rd = h2b[rd];
    f32x4 acc1[2], acc2[2];
#pragma unroll
    for (int n = 0; n < 2; ++n) { acc1[n] = 0.f; acc2[n] = 0.f; }

    // ---- issue ALL exchange loads (coalesced, in-flight) ----
    v4h ar1[16], ar2[32];
    if (p < STEPS) {
#pragma unroll
      for (int kt = 0; kt < 16; ++kt)
        ld_llc_v4h(h1rd + cbase + kt * 256, ar1[kt]);
    }
    if (p > 0) {
#pragma unroll
      for (int kt = 0; kt < 16; ++kt)
        ld_llc_v4h(nh1rd + cbase + kt * 256, ar2[kt]);
#pragma unroll
      for (int kt = 0; kt < 16; ++kt)
        ld_llc_v4h(h2rd + cbase + kt * 256, ar2[16 + kt]);
    }

    // ---- layer 1 x-part (plain loads; overlaps exchange-load latency) ----
    if (p < STEPS) {
      if constexpr (MODE == 2) {
        int aid = order[growA * 256 + p];
        const float* xp = (const float*)xsrc + (size_t)aid * 50;
#pragma unroll
        for (int kt = 0; kt < Dt; ++kt) {
          v4h a;
#pragma unroll
          for (int i = 0; i < 4; ++i) {
            int kk = kt * 16 + kg * 4 + i;
            a[i] = (kk < 50) ? (_Float16)xp[kk] : (_Float16)0.f;
          }
          mfma_pair(wlds + kt * 1024, csA, kg, a, acc1[0], acc1[1]);
        }
      } else {
        const _Float16* x16 = (const _Float16*)xsrc;
        const _Float16* xp;
        if constexpr (MODE == 0) {
          int so = order[growA * 128 + p];
          xp = x16 + ((size_t)growA * 128 + so) * 128;
        } else {
          xp = x16 + ((size_t)growA * 128 + p) * 128;
        }
#pragma unroll
        for (int kt = 0; kt < Dt; ++kt) {
          v4h a = *(const v4h*)(xp + kt * 16 + kg * 4);
          mfma_pair(wlds + kt * 1024, csA, kg, a, acc1[0], acc1[1]);
        }
      }
    }

    // ---- single drain for the exchange batch; fence MFMA hoisting ----
    asm volatile("s_waitcnt vmcnt(0)" ::: "memory");
    __builtin_amdgcn_sched_barrier(0);

    // ---- layer 1 h-part + layer 2, from registers ----
    if (p < STEPS) {
#pragma unroll
      for (int kt = 0; kt < 16; ++kt)
        mfma_pair(wlds + (Dt + kt) * 1024, csA, kg, ar1[kt], acc1[0], acc1[1]);
    }
    if (p > 0) {
#pragma unroll
      for (int kt = 0; kt < 32; ++kt)
        mfma_pair(w2 + kt * 1024, csA, kg, ar2[kt], acc2[0], acc2[1]);
    }

    // ---- pointwise layer 1 -> LDS stage ----
    if (p < STEPS) {
#pragma unroll
      for (int n = 0; n < 2; ++n) {
        float g0 = acc1[n][0], g1 = acc1[n][1], g2 = acc1[n][2], g3 = acc1[n][3];
        quadT(lane, g0, g1, g2, g3);
        float nc = sigf(g2 + bi1[n][2] + 1.f) * c1[n] + sigf(g0 + bi1[n][0]) * tanhf(g1 + bi1[n][1]);
        float nh = sigf(g3 + bi1[n][3]) * tanhf(nc);
        int cl = np * 8 + n * 4 + ul;
        stage[(mt * 16 + prow) * 16 + cl] = (_Float16)nh;           // UNMASKED
        if (p < lenP) { c1[n] = nc; h1st[n] = nh; }
        stage[1024 + (mt * 16 + prow) * 16 + cl] = (_Float16)h1st[n];
      }
    }
    // ---- pointwise layer 2 (t = p-1) -> LDS stage ----
    if (p > 0) {
#pragma unroll
      for (int n = 0; n < 2; ++n) {
        float g0 = acc2[n][0], g1 = acc2[n][1], g2 = acc2[n][2], g3 = acc2[n][3];
        quadT(lane, g0, g1, g2, g3);
        float nc = sigf(g2 + bi2[n][2] + 1.f) * c2[n] + sigf(g0 + bi2[n][0]) * tanhf(g1 + bi2[n][1]);
        float nh = sigf(g3 + bi2[n][3]) * tanhf(nc);
        int cl = np * 8 + n * 4 + ul;
        if (p - 1 < lenP) { c2[n] = nc; h2st[n] = nh; }
        stage[2048 + (mt * 16 + prow) * 16 + cl] = (_Float16)h2st[n];
      }
    }
    __syncthreads();  // stage tiles complete

    // ---- cooperative coalesced store into fragment layout ----
    for (int i = tid; i < 768; i += 512) {
      int tile = i >> 8;        // 0=nh1, 1=h1, 2=h2
      int rem = i & 255;
      int mtd = rem >> 6, kgd = (rem >> 4) & 3, ard = rem & 15;
      bool go = (tile == 2) ? (p > 0) : (p < STEPS);
      if (go) {
        v4h v = *(const v4h*)(stage + tile * 1024 + (mtd * 16 + ard) * 16 + kgd * 4);
        _Float16* dst = (tile == 0) ? nh1b[wr] : (tile == 1) ? h1b[wr] : h2b[wr];
        st_llc_v4h(dst + mtd * 4096 + g * 256 + kgd * 64 + ard * 4, v);
      }
    }

    if (p < STEPS) team_arrive_wait(flags, g, p + 1);
  }

#pragma unroll
  for (int n = 0; n < 2; ++n) {
    int ug = g * 16 + (2 * np + n) * 4 + ul;
    hcat[(size_t)growP * 768 + hoff + ug] = h2st[n];
  }
}

// 12 teams x 16 blocks, ALL XCD-pure (perf heuristic only; correctness is
// placement-independent via LLC-coherent exchange):
//   XCD0: stack0+stack1, XCD1: stack2+stack3,
//   XCD2: buff0+buff1,  XCD3: buff2+buff3,
//   XCD4-7: act0-3 (slots 16-31 exit).
__global__ __launch_bounds__(512, 2) void lstm_team_kernel(
    const _Float16* res16, const _Float16* buff16, const float* W_act,
    const int* sord, const int* haid,
    const int* slen, const int* blen, const int* alen,
    const _Float16* sWr, const _Float16* bWr, const _Float16* aWr,
    const float* sb1, const float* sb2, const float* bb1, const float* bb2,
    const float* ab1, const float* ab2,
    _Float16* exch, int* ctrs, float* hcat) {
  __shared__ __align__(16) _Float16 wlds[57344];  // 112 KB weight slice
  __shared__ __align__(16) _Float16 stage[3072];  // 6 KB pointwise staging

  const int bid = blockIdx.x;
  const int xcd = bid & 7, slot = bid >> 3;   // slot 0..31
  int tau, g;
  if (xcd < 4) {
    tau = xcd * 2 + (slot >> 4);   // 0..7: stack (xcd 0-1), buff (xcd 2-3)
    g = slot & 15;
  } else {
    if (slot >= 16) return;        // idle half of act XCDs
    tau = 8 + (xcd - 4);           // 8..11: act
    g = slot;
  }

  const _Float16* wsrc;
  int wn;
  if (tau < 4) { wsrc = sWr + (size_t)g * 57344; wn = 57344; }
  else if (tau < 8) { wsrc = bWr + (size_t)g * 57344; wn = 57344; }
  else { wsrc = aWr + (size_t)g * 53248; wn = 53248; }
  for (int i = threadIdx.x * 8; i < wn; i += 512 * 8)
    *(float4*)&wlds[i] = *(const float4*)&wsrc[i];
  __syncthreads();

  _Float16* ex = exch + (size_t)tau * 98304;
  int* flags = ctrs + tau * 32;

  if (tau < 4) {
    team_lstm<0, 8, 24, 128>(g, tau * 64, wlds, stage, res16, sord, slen, sb1, sb2, ex, flags, hcat, 0);
  } else if (tau < 8) {
    team_lstm<1, 8, 24, 128>(g, (tau - 4) * 64, wlds, stage, buff16, nullptr, blen, bb1, bb2, ex, flags, hcat, 256);
  } else {
    team_lstm<2, 4, 20, 256>(g, (tau - 8) * 64, wlds, stage, W_act, haid, alen, ab1, ab2, ex, flags, hcat, 512);
  }
}

// ---------------------------------------------------------------------------
// Final projection: out[b] = hcat[b] @ fW + fb   (256 x 768) @ (768 x 82)
// ---------------------------------------------------------------------------
__global__ __launch_bounds__(128) void final_kernel(
    const float* __restrict__ hcat, const float* __restrict__ fW,
    const float* __restrict__ fb, float* __restrict__ out) {
  __shared__ float hrow[768];
  const int b = blockIdx.x;
  const int tid = threadIdx.x;
  for (int k = tid; k < 768; k += 128) hrow[k] = hcat[(size_t)b * 768 + k];
  __syncthreads();
  if (tid < kNACT) {
    float acc = fb[tid];
#pragma unroll 8
    for (int k = 0; k < 768; ++k) acc = fmaf(hrow[k], fW[k * kNACT + tid], acc);
    out[(size_t)b * kNACT + tid] = acc;
  }
}

}  // namespace

extern "C" void kernel_launch(void* const* d_in, const int* in_sizes, int n_in,
                              void* d_out, int out_size, void* d_ws, size_t ws_size,
                              hipStream_t stream) {
  const int* twid = (const int*)d_in[0];
  const int* tpid = (const int*)d_in[1];
  const int* bwid = (const int*)d_in[2];
  const int* bpid = (const int*)d_in[3];
  const int* relid = (const int*)d_in[4];
  const int* haid = (const int*)d_in[5];
  const int* head = (const int*)d_in[6];
  const int* depo = (const int*)d_in[7];
  const int* leaf = (const int*)d_in[8];
  const int* sord = (const int*)d_in[9];
  const int* slen = (const int*)d_in[10];
  const int* blen = (const int*)d_in[11];
  const int* alen = (const int*)d_in[12];
  const float* W_word = (const float*)d_in[13];
  const float* W_pos = (const float*)d_in[14];
  const float* W_rel = (const float*)d_in[15];
  const float* W_act = (const float*)d_in[16];
  const float* emb_W = (const float*)d_in[17];
  const float* emb_b = (const float*)d_in[18];
  const float* rec_W = (const float*)d_in[19];
  const float* rec_b = (const float*)d_in[20];
  const float* sW1 = (const float*)d_in[21];
  const float* sb1 = (const float*)d_in[22];
  const float* sW2 = (const float*)d_in[23];
  const float* sb2 = (const float*)d_in[24];
  const float* bW1 = (const float*)d_in[25];
  const float* bb1 = (const float*)d_in[26];
  const float* bW2 = (const float*)d_in[27];
  const float* bb2 = (const float*)d_in[28];
  const float* aW1 = (const float*)d_in[29];
  const float* ab1 = (const float*)d_in[30];
  const float* aW2 = (const float*)d_in[31];
  const float* ab2 = (const float*)d_in[32];
  const float* fW = (const float*)d_in[33];
  const float* fb = (const float*)d_in[34];

  // ---- workspace carve-up ----
  char* w = (char*)d_ws;
  float* tree_emb = (float*)w;            w += (size_t)kB * kT * kFC * 4;
  _Float16* buff16 = (_Float16*)w;        w += (size_t)kB * kT * kFC * 2;
  _Float16* res16 = (_Float16*)w;         w += (size_t)kB * kT * kFC * 2;
  float* hcat = (float*)w;                w += (size_t)kB * 768 * 4;
  _Float16* sWr = (_Float16*)w;           w += (size_t)57344 * 16 * 2;
  _Float16* bWr = (_Float16*)w;           w += (size_t)57344 * 16 * 2;
  _Float16* aWr = (_Float16*)w;           w += (size_t)53248 * 16 * 2;
  _Float16* exch = (_Float16*)w;          w += (size_t)12 * 98304 * 2;
  int* ctrs = (int*)w;                    w += (size_t)12 * 32 * 4;
  size_t needed = (size_t)(w - (char*)d_ws);
  if (ws_size < needed) return;

  // 0) zero exchange buffers + barrier flags (every launch; deterministic)
  (void)hipMemsetAsync(exch, 0, (size_t)12 * 98304 * 2 + (size_t)12 * 32 * 4, stream);

  // 1) team-layout fp16 weight reorder
  auto reorder = [&](const float* W, _Float16* Wr, int Kt, int D, int Dpad, int gstride) {
    int total = 16 * Kt * 1024;
    reorder_team_kernel<<<(total + 255) / 256, 256, 0, stream>>>(W, Wr, Kt, D, Dpad, gstride, total);
  };
  reorder(sW1, sWr, 24, 128, 128, 57344);
  reorder(sW2, sWr + 24 * 1024, 32, 512, 512, 57344);
  reorder(bW1, bWr, 24, 128, 128, 57344);
  reorder(bW2, bWr + 24 * 1024, 32, 512, 512, 57344);
  reorder(aW1, aWr, 20, 50, 64, 53248);
  reorder(aW2, aWr + 20 * 1024, 32, 512, 512, 53248);

  // 2) embeddings (tree f32, buff fp16)
  emb_kernel<<<(2 * kB * kT) / 8, 128, 0, stream>>>(
      twid, tpid, bwid, bpid, W_word, W_pos, emb_W, emb_b, tree_emb, buff16);

  // 3) tree composition scan -> fp16 (rec_W staged in LDS)
  tree_scan_kernel<<<kB, 128, 0, stream>>>(
      tree_emb, head, depo, relid, leaf, W_rel, rec_W, rec_b, res16);

  // 4) persistent-weight team LSTMs (cooperative: residency guarantee)
  {
    const _Float16* a0 = res16; const _Float16* a1 = buff16; const float* a2 = W_act;
    const int* a3 = sord; const int* a4 = haid;
    const int* a5 = slen; const int* a6 = blen; const int* a7 = alen;
    const _Float16* a8 = sWr; const _Float16* a9 = bWr; const _Float16* a10 = aWr;
    const float* a11 = sb1; const float* a12 = sb2; const float* a13 = bb1; const float* a14 = bb2;
    const float* a15 = ab1; const float* a16 = ab2;
    _Float16* a17 = exch; int* a18 = ctrs; float* a19 = hcat;
    void* kargs[] = {&a0, &a1, &a2, &a3, &a4, &a5, &a6, &a7, &a8, &a9, &a10,
                     &a11, &a12, &a13, &a14, &a15, &a16, &a17, &a18, &a19};
    (void)hipLaunchCooperativeKernel((const void*)lstm_team_kernel, dim3(256), dim3(512),
                                     kargs, 0, stream);
  }

  // 5) output projection
  final_kernel<<<kB, 128, 0, stream>>>(hcat, fW, fb, (float*)d_out);
}

// Round 14
// 2852.217 us; speedup vs baseline: 1.8336x; 1.0496x over previous
//
#include <hip/hip_runtime.h>
#include <hip/hip_fp16.h>
#include <math.h>

namespace {

constexpr int kB = 256;
constexpr int kT = 128;
constexpr int kFC = 128;
constexpr int kNACT = 82;
constexpr int kWDIM = 300;
constexpr int kPOS = 50;

typedef _Float16 v4h __attribute__((ext_vector_type(4)));
typedef float f32x4 __attribute__((ext_vector_type(4)));

__device__ __forceinline__ float sigf(float x) { return 1.0f / (1.0f + expf(-x)); }

// Exchange data ops.
// FAST (team runtime-verified single-XCD): plain write-back store (acks at the
// shared L2) + sc0-only load (bypasses per-CU L1, served by the SAME L2).
// SLOW (any placement): sc0 sc1 LLC-coherent (R9/R13-proven).
template <bool FAST>
__device__ __forceinline__ void ld_ex(const _Float16* p, v4h& dst) {
  if constexpr (FAST)
    asm volatile("global_load_dwordx2 %0, %1, off sc0" : "=v"(dst) : "v"(p));
  else
    asm volatile("global_load_dwordx2 %0, %1, off sc0 sc1" : "=v"(dst) : "v"(p));
}
template <bool FAST>
__device__ __forceinline__ void st_ex(_Float16* p, v4h v) {
  if constexpr (FAST)
    asm volatile("global_store_dwordx2 %0, %1, off" :: "v"(p), "v"(v) : "memory");
  else
    asm volatile("global_store_dwordx2 %0, %1, off sc0 sc1" :: "v"(p), "v"(v) : "memory");
}

// Team barrier: per-block arrival flags, ONE CACHE LINE PER BLOCK (stride 16
// ints) to avoid arrival-line ping-pong. Flags always agent-atomic (proven —
// deadlock-impossible). vmcnt(0) drains this wave's exchange stores;
// __syncthreads joins waves; thread 0 publishes; waves poll coalesced.
__device__ __forceinline__ void team_arrive_wait(int* flags, int g, int target) {
  asm volatile("s_waitcnt vmcnt(0)" ::: "memory");
  __syncthreads();
  if (threadIdx.x == 0)
    __hip_atomic_store(flags + g * 16, target, __ATOMIC_RELAXED, __HIP_MEMORY_SCOPE_AGENT);
  const int lane = threadIdx.x & 63;
  for (;;) {
    int f = __hip_atomic_load(flags + (lane & 15) * 16, __ATOMIC_RELAXED, __HIP_MEMORY_SCOPE_AGENT);
    if (__all(f >= target)) break;
    __builtin_amdgcn_s_sleep(1);
  }
}

// 4x4 transpose across lane quads: 4 regs x (rows) -> 4 regs x (gates).
__device__ __forceinline__ void quadT(int lane, float& a0, float& a1, float& a2, float& a3) {
  {
    bool odd = lane & 1;
    float s0 = odd ? a0 : a1;
    float s1 = odd ? a2 : a3;
    float r0 = __shfl_xor(s0, 1);
    float r1 = __shfl_xor(s1, 1);
    if (odd) { a0 = r0; a2 = r1; } else { a1 = r0; a3 = r1; }
  }
  {
    bool hi = lane & 2;
    float s0 = hi ? a0 : a2;
    float s1 = hi ? a1 : a3;
    float r0 = __shfl_xor(s0, 2);
    float r1 = __shfl_xor(s1, 2);
    if (hi) { a0 = r0; a1 = r1; } else { a2 = r0; a3 = r1; }
  }
}

// B-frag read (bank-conflict-aware) + 2 MFMAs (ntile pair).
__device__ __forceinline__ void mfma_pair(const _Float16* wt, int csA, int kg, v4h a,
                                          f32x4& q0, f32x4& q1) {
  const _Float16* wp = wt + kg * 256 + csA * 4;
  v4h b0 = *(const v4h*)(wp);
  q0 = __builtin_amdgcn_mfma_f32_16x16x16f16(a, b0, q0, 0, 0, 0);
  v4h b1 = *(const v4h*)(wp + 64);
  q1 = __builtin_amdgcn_mfma_f32_16x16x16f16(a, b1, q1, 0, 0, 0);
}

// ---------------------------------------------------------------------------
// Reorder W (K,1024) fp32 -> fp16 team layout:
// Wr[g][kt][kg][cs][ki] with col' = g*64+cs = 4u+gate, k = kt*16+kg*4+ki.
// ---------------------------------------------------------------------------
__global__ void reorder_team_kernel(const float* __restrict__ W, _Float16* __restrict__ Wr,
                                    int Ktiles, int D, int Dpad, int gstride, int total) {
  int idx = blockIdx.x * 256 + threadIdx.x;
  if (idx >= total) return;
  int per = Ktiles << 10;
  int g = idx / per;
  int rem = idx - g * per;
  int kt = rem >> 10;
  int r2 = rem & 1023;
  int kg = r2 >> 8, cs = (r2 >> 2) & 63, ki = r2 & 3;
  int k = kt * 16 + kg * 4 + ki;
  int src = (k < Dpad) ? ((k < D) ? k : -1) : (D + (k - Dpad));
  int colp = g * 64 + cs;
  int u = colp >> 2, gate = colp & 3;
  _Float16 v = (_Float16)0.f;
  if (src >= 0) v = (_Float16)W[(size_t)src * 1024 + gate * 256 + u];
  Wr[(size_t)g * gstride + rem] = v;
}

// ---------------------------------------------------------------------------
// Embeddings: relu(concat(W_word[wid], W_pos[pid]) @ emb_W + emb_b)
// ---------------------------------------------------------------------------
__global__ __launch_bounds__(128) void emb_kernel(
    const int* __restrict__ twid, const int* __restrict__ tpid,
    const int* __restrict__ bwid, const int* __restrict__ bpid,
    const float* __restrict__ W_word, const float* __restrict__ W_pos,
    const float* __restrict__ emb_W, const float* __restrict__ emb_b,
    float* __restrict__ tree_emb, _Float16* __restrict__ buff16) {
  __shared__ float xs[8][352];
  const int tid = threadIdx.x;
  const int pair0 = blockIdx.x * 8;
  const int NTREE = kB * kT;

  for (int p = 0; p < 8; ++p) {
    int P = pair0 + p;
    bool isTree = P < NTREE;
    int idx = isTree ? P : P - NTREE;
    int wid = isTree ? twid[idx] : bwid[idx];
    int pid = isTree ? tpid[idx] : bpid[idx];
    const float* wrow = W_word + (size_t)wid * kWDIM;
    for (int k = tid; k < kWDIM; k += 128) xs[p][k] = wrow[k];
    if (tid < kPOS) xs[p][kWDIM + tid] = W_pos[pid * kPOS + tid];
  }
  __syncthreads();

  float acc[8];
  const float bj = emb_b[tid];
#pragma unroll
  for (int p = 0; p < 8; ++p) acc[p] = bj;

#pragma unroll 10
  for (int k = 0; k < kWDIM + kPOS; ++k) {
    float w = emb_W[k * kFC + tid];
#pragma unroll
    for (int p = 0; p < 8; ++p) acc[p] = fmaf(xs[p][k], w, acc[p]);
  }

  for (int p = 0; p < 8; ++p) {
    int P = pair0 + p;
    bool isTree = P < NTREE;
    int idx = isTree ? P : P - NTREE;
    float v = fmaxf(acc[p], 0.0f);
    if (isTree) tree_emb[(size_t)idx * kFC + tid] = v;
    else buff16[(size_t)idx * kFC + tid] = (_Float16)v;
  }
}

// ---------------------------------------------------------------------------
// Tree composition scan: one block per batch row, res[128][128] f32 in LDS.
// rec_W staged ONCE as fp16 in LDS (78 KB).
// ---------------------------------------------------------------------------
__global__ __launch_bounds__(128) void tree_scan_kernel(
    const float* __restrict__ tree_emb,
    const int* __restrict__ head_ord, const int* __restrict__ dep_ord,
    const int* __restrict__ rel_id, const int* __restrict__ is_leaf,
    const float* __restrict__ W_rel,
    const float* __restrict__ rec_W, const float* __restrict__ rec_b,
    _Float16* __restrict__ res16) {
  __shared__ float res[kT][kFC];          // 64 KB
  __shared__ _Float16 w16[306 * kFC];     // 78336 B
  const int b = blockIdx.x;
  const int j = threadIdx.x;

  for (int idx = j; idx < 306 * kFC; idx += 128)
    w16[idx] = (_Float16)rec_W[idx];

  res[0][j] = tree_emb[((size_t)b * kT) * kFC + j];
  const float rb = rec_b[j];
  __syncthreads();

  const _Float16* wj = w16 + j;
  for (int i = 1; i < kT; ++i) {
    const int base = b * kT + i;
    const int leaf = is_leaf[base];
    if (leaf > 0) {
      res[i][j] = tree_emb[(size_t)base * kFC + j];
    } else {
      const int hi = head_ord[base];
      const int di = dep_ord[base];
      const int rid = rel_id[base];
      float acc = rb;
#pragma unroll 8
      for (int k = 0; k < 128; ++k)
        acc = fmaf(res[hi][k], (float)wj[k * kFC], acc);
#pragma unroll 5
      for (int k = 0; k < 50; ++k)
        acc = fmaf(W_rel[rid * 50 + k], (float)wj[(128 + k) * kFC], acc);
#pragma unroll 8
      for (int k = 0; k < 128; ++k)
        acc = fmaf(res[di][k], (float)wj[(178 + k) * kFC], acc);
      res[i][j] = tanhf(acc);
    }
    __syncthreads();
  }

  for (int idx = j; idx < kT * kFC; idx += 128) {
    int t = idx >> 7;
    int jj = idx & 127;
    res16[((size_t)b * kT + t) * kFC + jj] = (_Float16)res[t][jj];
  }
}

// ---------------------------------------------------------------------------
// Persistent-weight team LSTM (R9/R13 structure, (mt,np) wave split).
// Exchange tiles: fragment-coalesced ex[mt][kt][kg][arow][ki]. FAST teams use
// same-XCD L2 semantics; SLOW teams use LLC semantics. Flags agent-atomic.
// ---------------------------------------------------------------------------
template <int MODE, int Dt, int K1t, int STEPS, bool FAST>
__device__ void team_lstm(
    int g, int row0, const _Float16* wlds, _Float16* stage,  // stage: [3][64][16] LDS
    const void* xsrc, const int* __restrict__ order,
    const int* __restrict__ lengths,
    const float* __restrict__ b1, const float* __restrict__ b2,
    _Float16* exch, int* flags, float* __restrict__ hcat, int hoff) {
  static_assert(K1t - Dt == 16, "h1 tile must be 16 k-tiles");
  const int tid = threadIdx.x, lane = tid & 63;
  const int wave = tid >> 6, mt = wave >> 1, np = wave & 1;
  const int arow = lane & 15, kg = lane >> 4;
  const int prow = kg * 4 + (lane & 3);
  const int ul = arow >> 2;
  const int csA = np * 32 + arow;

  _Float16* nh1b[2] = {exch, exch + 16384};
  _Float16* h1b[2] = {exch + 32768, exch + 49152};
  _Float16* h2b[2] = {exch + 65536, exch + 81920};

  const int growA = row0 + mt * 16 + arow;
  const int growP = row0 + mt * 16 + prow;
  const int lenP = lengths[growP];

  // consumer base into fragment-coalesced tile: 8*lane bytes within a kt slab
  const int cbase = mt * 4096 + kg * 64 + arow * 4;

  float bi1[2][4], bi2[2][4];
#pragma unroll
  for (int n = 0; n < 2; ++n) {
    int ug = g * 16 + (2 * np + n) * 4 + ul;
#pragma unroll
    for (int q = 0; q < 4; ++q) {
      bi1[n][q] = b1[q * 256 + ug];
      bi2[n][q] = b2[q * 256 + ug];
    }
  }
  float c1[2] = {0.f, 0.f}, h1st[2] = {0.f, 0.f};
  float c2[2] = {0.f, 0.f}, h2st[2] = {0.f, 0.f};
  const _Float16* w2 = wlds + K1t * 1024;

  for (int p = 0; p <= STEPS; ++p) {
    const int rd = (p + 1) & 1, wr = p & 1;
    const _Float16* h1rd = h1b[rd];
    const _Float16* nh1rd = nh1b[rd];
    const _Float16* h2rd = h2b[rd];
    f32x4 acc1[2], acc2[2];
#pragma unroll
    for (int n = 0; n < 2; ++n) { acc1[n] = 0.f; acc2[n] = 0.f; }

    // ---- issue ALL exchange loads (coalesced, in-flight) ----
    v4h ar1[16], ar2[32];
    if (p < STEPS) {
#pragma unroll
      for (int kt = 0; kt < 16; ++kt)
        ld_ex<FAST>(h1rd + cbase + kt * 256, ar1[kt]);
    }
    if (p > 0) {
#pragma unroll
      for (int kt = 0; kt < 16; ++kt)
        ld_ex<FAST>(nh1rd + cbase + kt * 256, ar2[kt]);
#pragma unroll
      for (int kt = 0; kt < 16; ++kt)
        ld_ex<FAST>(h2rd + cbase + kt * 256, ar2[16 + kt]);
    }

    // ---- layer 1 x-part (plain loads; overlaps exchange-load latency) ----
    if (p < STEPS) {
      if constexpr (MODE == 2) {
        int aid = order[growA * 256 + p];
        const float* xp = (const float*)xsrc + (size_t)aid * 50;
#pragma unroll
        for (int kt = 0; kt < Dt; ++kt) {
          v4h a;
#pragma unroll
          for (int i = 0; i < 4; ++i) {
            int kk = kt * 16 + kg * 4 + i;
            a[i] = (kk < 50) ? (_Float16)xp[kk] : (_Float16)0.f;
          }
          mfma_pair(wlds + kt * 1024, csA, kg, a, acc1[0], acc1[1]);
        }
      } else {
        const _Float16* x16 = (const _Float16*)xsrc;
        const _Float16* xp;
        if constexpr (MODE == 0) {
          int so = order[growA * 128 + p];
          xp = x16 + ((size_t)growA * 128 + so) * 128;
        } else {
          xp = x16 + ((size_t)growA * 128 + p) * 128;
        }
#pragma unroll
        for (int kt = 0; kt < Dt; ++kt) {
          v4h a = *(const v4h*)(xp + kt * 16 + kg * 4);
          mfma_pair(wlds + kt * 1024, csA, kg, a, acc1[0], acc1[1]);
        }
      }
    }

    // ---- single drain for the exchange batch; fence MFMA hoisting ----
    asm volatile("s_waitcnt vmcnt(0)" ::: "memory");
    __builtin_amdgcn_sched_barrier(0);

    // ---- layer 1 h-part + layer 2, from registers ----
    if (p < STEPS) {
#pragma unroll
      for (int kt = 0; kt < 16; ++kt)
        mfma_pair(wlds + (Dt + kt) * 1024, csA, kg, ar1[kt], acc1[0], acc1[1]);
    }
    if (p > 0) {
#pragma unroll
      for (int kt = 0; kt < 32; ++kt)
        mfma_pair(w2 + kt * 1024, csA, kg, ar2[kt], acc2[0], acc2[1]);
    }

    // ---- pointwise layer 1 -> LDS stage ----
    if (p < STEPS) {
#pragma unroll
      for (int n = 0; n < 2; ++n) {
        float g0 = acc1[n][0], g1 = acc1[n][1], g2 = acc1[n][2], g3 = acc1[n][3];
        quadT(lane, g0, g1, g2, g3);
        float nc = sigf(g2 + bi1[n][2] + 1.f) * c1[n] + sigf(g0 + bi1[n][0]) * tanhf(g1 + bi1[n][1]);
        float nh = sigf(g3 + bi1[n][3]) * tanhf(nc);
        int cl = np * 8 + n * 4 + ul;
        stage[(mt * 16 + prow) * 16 + cl] = (_Float16)nh;           // UNMASKED
        if (p < lenP) { c1[n] = nc; h1st[n] = nh; }
        stage[1024 + (mt * 16 + prow) * 16 + cl] = (_Float16)h1st[n];
      }
    }
    // ---- pointwise layer 2 (t = p-1) -> LDS stage ----
    if (p > 0) {
#pragma unroll
      for (int n = 0; n < 2; ++n) {
        float g0 = acc2[n][0], g1 = acc2[n][1], g2 = acc2[n][2], g3 = acc2[n][3];
        quadT(lane, g0, g1, g2, g3);
        float nc = sigf(g2 + bi2[n][2] + 1.f) * c2[n] + sigf(g0 + bi2[n][0]) * tanhf(g1 + bi2[n][1]);
        float nh = sigf(g3 + bi2[n][3]) * tanhf(nc);
        int cl = np * 8 + n * 4 + ul;
        if (p - 1 < lenP) { c2[n] = nc; h2st[n] = nh; }
        stage[2048 + (mt * 16 + prow) * 16 + cl] = (_Float16)h2st[n];
      }
    }
    __syncthreads();  // stage tiles complete

    // ---- cooperative coalesced store into fragment layout ----
    for (int i = tid; i < 768; i += 512) {
      int tile = i >> 8;        // 0=nh1, 1=h1, 2=h2
      int rem = i & 255;
      int mtd = rem >> 6, kgd = (rem >> 4) & 3, ard = rem & 15;
      bool go = (tile == 2) ? (p > 0) : (p < STEPS);
      if (go) {
        v4h v = *(const v4h*)(stage + tile * 1024 + (mtd * 16 + ard) * 16 + kgd * 4);
        _Float16* dst = (tile == 0) ? nh1b[wr] : (tile == 1) ? h1b[wr] : h2b[wr];
        st_ex<FAST>(dst + mtd * 4096 + g * 256 + kgd * 64 + ard * 4, v);
      }
    }

    if (p < STEPS) team_arrive_wait(flags, g, p + 1);
  }

#pragma unroll
  for (int n = 0; n < 2; ++n) {
    int ug = g * 16 + (2 * np + n) * 4 + ul;
    hcat[(size_t)growP * 768 + hoff + ug] = h2st[n];
  }
}

// 12 teams x 16 blocks, XCD-pure mapping (heuristic). Each team verifies at
// runtime that all 16 blocks share one XCC (equality check via agent atomics);
// verified -> FAST L2-local data exchange, else -> SLOW LLC (R9 semantics).
__global__ __launch_bounds__(512, 2) void lstm_team_kernel(
    const _Float16* res16, const _Float16* buff16, const float* W_act,
    const int* sord, const int* haid,
    const int* slen, const int* blen, const int* alen,
    const _Float16* sWr, const _Float16* bWr, const _Float16* aWr,
    const float* sb1, const float* sb2, const float* bb1, const float* bb2,
    const float* ab1, const float* ab2,
    _Float16* exch, int* ctrs, float* hcat) {
  __shared__ __align__(16) _Float16 wlds[57344];  // 112 KB weight slice
  __shared__ __align__(16) _Float16 stage[3072];  // 6 KB pointwise staging

  const int bid = blockIdx.x;
  const int xcd = bid & 7, slot = bid >> 3;   // slot 0..31
  int tau, g;
  if (xcd < 4) {
    tau = xcd * 2 + (slot >> 4);   // 0..7: stack (xcd 0-1), buff (xcd 2-3)
    g = slot & 15;
  } else {
    if (slot >= 16) return;        // idle half of act XCDs
    tau = 8 + (xcd - 4);           // 8..11: act
    g = slot;
  }

  // ---- publish this block's XCC id (+1 so 0 = not-yet-arrived) ----
  int* chk = ctrs + 3072 + tau * 16;
  {
    unsigned xcc;
    asm volatile("s_getreg_b32 %0, hwreg(HW_REG_XCC_ID)" : "=s"(xcc));
    if (threadIdx.x == 0)
      __hip_atomic_store(chk + g, (int)(xcc & 0xf) + 1,
                         __ATOMIC_RELAXED, __HIP_MEMORY_SCOPE_AGENT);
  }

  // ---- load weight slice into LDS (overlaps check propagation) ----
  const _Float16* wsrc;
  int wn;
  if (tau < 4) { wsrc = sWr + (size_t)g * 57344; wn = 57344; }
  else if (tau < 8) { wsrc = bWr + (size_t)g * 57344; wn = 57344; }
  else { wsrc = aWr + (size_t)g * 53248; wn = 53248; }
  for (int i = threadIdx.x * 8; i < wn; i += 512 * 8)
    *(float4*)&wlds[i] = *(const float4*)&wsrc[i];

  // ---- collect team placement verdict (all 16 equal -> FAST) ----
  bool fast;
  {
    const int lane = threadIdx.x & 63;
    int v;
    for (;;) {
      v = __hip_atomic_load(chk + (lane & 15), __ATOMIC_RELAXED, __HIP_MEMORY_SCOPE_AGENT);
      if (__all(v != 0)) break;
      __builtin_amdgcn_s_sleep(1);
    }
    int v0 = __shfl(v, 0);
    fast = __all(v == v0);
  }
  __syncthreads();

  _Float16* ex = exch + (size_t)tau * 98304;
  int* flags = ctrs + tau * 256;   // 16 flags x 16-int stride (1 line each)

  if (tau < 4) {
    if (fast) team_lstm<0, 8, 24, 128, true>(g, tau * 64, wlds, stage, res16, sord, slen, sb1, sb2, ex, flags, hcat, 0);
    else      team_lstm<0, 8, 24, 128, false>(g, tau * 64, wlds, stage, res16, sord, slen, sb1, sb2, ex, flags, hcat, 0);
  } else if (tau < 8) {
    if (fast) team_lstm<1, 8, 24, 128, true>(g, (tau - 4) * 64, wlds, stage, buff16, nullptr, blen, bb1, bb2, ex, flags, hcat, 256);
    else      team_lstm<1, 8, 24, 128, false>(g, (tau - 4) * 64, wlds, stage, buff16, nullptr, blen, bb1, bb2, ex, flags, hcat, 256);
  } else {
    if (fast) team_lstm<2, 4, 20, 256, true>(g, (tau - 8) * 64, wlds, stage, W_act, haid, alen, ab1, ab2, ex, flags, hcat, 512);
    else      team_lstm<2, 4, 20, 256, false>(g, (tau - 8) * 64, wlds, stage, W_act, haid, alen, ab1, ab2, ex, flags, hcat, 512);
  }
}

// ---------------------------------------------------------------------------
// Final projection: out[b] = hcat[b] @ fW + fb   (256 x 768) @ (768 x 82)
// ---------------------------------------------------------------------------
__global__ __launch_bounds__(128) void final_kernel(
    const float* __restrict__ hcat, const float* __restrict__ fW,
    const float* __restrict__ fb, float* __restrict__ out) {
  __shared__ float hrow[768];
  const int b = blockIdx.x;
  const int tid = threadIdx.x;
  for (int k = tid; k < 768; k += 128) hrow[k] = hcat[(size_t)b * 768 + k];
  __syncthreads();
  if (tid < kNACT) {
    float acc = fb[tid];
#pragma unroll 8
    for (int k = 0; k < 768; ++k) acc = fmaf(hrow[k], fW[k * kNACT + tid], acc);
    out[(size_t)b * kNACT + tid] = acc;
  }
}

}  // namespace

extern "C" void kernel_launch(void* const* d_in, const int* in_sizes, int n_in,
                              void* d_out, int out_size, void* d_ws, size_t ws_size,
                              hipStream_t stream) {
  const int* twid = (const int*)d_in[0];
  const int* tpid = (const int*)d_in[1];
  const int* bwid = (const int*)d_in[2];
  const int* bpid = (const int*)d_in[3];
  const int* relid = (const int*)d_in[4];
  const int* haid = (const int*)d_in[5];
  const int* head = (const int*)d_in[6];
  const int* depo = (const int*)d_in[7];
  const int* leaf = (const int*)d_in[8];
  const int* sord = (const int*)d_in[9];
  const int* slen = (const int*)d_in[10];
  const int* blen = (const int*)d_in[11];
  const int* alen = (const int*)d_in[12];
  const float* W_word = (const float*)d_in[13];
  const float* W_pos = (const float*)d_in[14];
  const float* W_rel = (const float*)d_in[15];
  const float* W_act = (const float*)d_in[16];
  const float* emb_W = (const float*)d_in[17];
  const float* emb_b = (const float*)d_in[18];
  const float* rec_W = (const float*)d_in[19];
  const float* rec_b = (const float*)d_in[20];
  const float* sW1 = (const float*)d_in[21];
  const float* sb1 = (const float*)d_in[22];
  const float* sW2 = (const float*)d_in[23];
  const float* sb2 = (const float*)d_in[24];
  const float* bW1 = (const float*)d_in[25];
  const float* bb1 = (const float*)d_in[26];
  const float* bW2 = (const float*)d_in[27];
  const float* bb2 = (const float*)d_in[28];
  const float* aW1 = (const float*)d_in[29];
  const float* ab1 = (const float*)d_in[30];
  const float* aW2 = (const float*)d_in[31];
  const float* ab2 = (const float*)d_in[32];
  const float* fW = (const float*)d_in[33];
  const float* fb = (const float*)d_in[34];

  // ---- workspace carve-up ----
  char* w = (char*)d_ws;
  float* tree_emb = (float*)w;            w += (size_t)kB * kT * kFC * 4;
  _Float16* buff16 = (_Float16*)w;        w += (size_t)kB * kT * kFC * 2;
  _Float16* res16 = (_Float16*)w;         w += (size_t)kB * kT * kFC * 2;
  float* hcat = (float*)w;                w += (size_t)kB * 768 * 4;
  _Float16* sWr = (_Float16*)w;           w += (size_t)57344 * 16 * 2;
  _Float16* bWr = (_Float16*)w;           w += (size_t)57344 * 16 * 2;
  _Float16* aWr = (_Float16*)w;           w += (size_t)53248 * 16 * 2;
  _Float16* exch = (_Float16*)w;          w += (size_t)12 * 98304 * 2;
  int* ctrs = (int*)w;                    w += (size_t)3328 * 4;  // flags 12*256 + chk 12*16
  size_t needed = (size_t)(w - (char*)d_ws);
  if (ws_size < needed) return;

  // 0) zero exchange buffers + flags + placement-check slots
  (void)hipMemsetAsync(exch, 0, (size_t)12 * 98304 * 2 + (size_t)3328 * 4, stream);

  // 1) team-layout fp16 weight reorder
  auto reorder = [&](const float* W, _Float16* Wr, int Kt, int D, int Dpad, int gstride) {
    int total = 16 * Kt * 1024;
    reorder_team_kernel<<<(total + 255) / 256, 256, 0, stream>>>(W, Wr, Kt, D, Dpad, gstride, total);
  };
  reorder(sW1, sWr, 24, 128, 128, 57344);
  reorder(sW2, sWr + 24 * 1024, 32, 512, 512, 57344);
  reorder(bW1, bWr, 24, 128, 128, 57344);
  reorder(bW2, bWr + 24 * 1024, 32, 512, 512, 57344);
  reorder(aW1, aWr, 20, 50, 64, 53248);
  reorder(aW2, aWr + 20 * 1024, 32, 512, 512, 53248);

  // 2) embeddings (tree f32, buff fp16)
  emb_kernel<<<(2 * kB * kT) / 8, 128, 0, stream>>>(
      twid, tpid, bwid, bpid, W_word, W_pos, emb_W, emb_b, tree_emb, buff16);

  // 3) tree composition scan -> fp16 (rec_W staged in LDS)
  tree_scan_kernel<<<kB, 128, 0, stream>>>(
      tree_emb, head, depo, relid, leaf, W_rel, rec_W, rec_b, res16);

  // 4) persistent-weight team LSTMs (cooperative: residency guarantee)
  {
    const _Float16* a0 = res16; const _Float16* a1 = buff16; const float* a2 = W_act;
    const int* a3 = sord; const int* a4 = haid;
    const int* a5 = slen; const int* a6 = blen; const int* a7 = alen;
    const _Float16* a8 = sWr; const _Float16* a9 = bWr; const _Float16* a10 = aWr;
    const float* a11 = sb1; const float* a12 = sb2; const float* a13 = bb1; const float* a14 = bb2;
    const float* a15 = ab1; const float* a16 = ab2;
    _Float16* a17 = exch; int* a18 = ctrs; float* a19 = hcat;
    void* kargs[] = {&a0, &a1, &a2, &a3, &a4, &a5, &a6, &a7, &a8, &a9, &a10,
                     &a11, &a12, &a13, &a14, &a15, &a16, &a17, &a18, &a19};
    (void)hipLaunchCooperativeKernel((const void*)lstm_team_kernel, dim3(256), dim3(512),
                                     kargs, 0, stream);
  }

  // 5) output projection
  final_kernel<<<kB, 128, 0, stream>>>(hcat, fW, fb, (float*)d_out);
}